// Round 6
// baseline (3368.373 us; speedup 1.0000x reference)
//
#include <hip/hip_runtime.h>
#include <hip/hip_bf16.h>
#include <math.h>

// LinearTransformerAgent R6 (= R5 resubmit; R5 bench was a broker timeout).
// m97-structure GEMM (global_load_lds w=16, linear LDS, 2-barrier loop) +
// embed as gather+MFMA. attn unchanged from R4.
// B=64 T=512 D=512 H=8 DH=64 L=4 DFF=2048, ROWS=32768, row-chunks of 8192.
// ws 132.1 MB: x f32 64 | h bf16 8 | big bf16 32 | Wt bf16 24 | obs_bf 4 | wobs .06

#define B_    64
#define T_    512
#define D_    512
#define H_    8
#define L_    4
#define NACT  16
#define DFF   2048
#define ROWS  (B_ * T_)
#define RC_   4
#define CH_ROWS (ROWS / RC_)     // 8192
#define CH_B  (B_ / RC_)         // 16

typedef __attribute__((ext_vector_type(8))) short short8;
typedef __attribute__((ext_vector_type(4))) float f32x4;
#define MFMA16(a, b, c) __builtin_amdgcn_mfma_f32_16x16x32_bf16(a, b, c, 0, 0, 0)

// async global->LDS, 16B per lane; LDS dest must be wave-base + lane*16
#define GLOAD16(gp, lp) __builtin_amdgcn_global_load_lds( \
    (const __attribute__((address_space(1))) void*)(gp),  \
    (__attribute__((address_space(3))) void*)(lp), 16, 0, 0)

__device__ __forceinline__ ushort f2bf(float f) {
    union { float f; unsigned u; } c; c.f = f;
    unsigned r = c.u + 0x7FFF + ((c.u >> 16) & 1);
    return (ushort)(r >> 16);
}
__device__ __forceinline__ float gelu_tanh(float v) {
    float u = 0.7978845608028654f * (v + 0.044715f * v * v * v);
    return 0.5f * v * (1.0f + tanhf(u));
}
__device__ __forceinline__ float wave_sum(float v) {
#pragma unroll
    for (int o = 32; o > 0; o >>= 1) v += __shfl_xor(v, o);
    return v;
}
// XOR-swizzled byte offset into a [rows][128B] LDS tile (attn only)
__device__ __forceinline__ int sw(int row, int kb) {
    return row * 128 + (kb ^ ((row & 7) << 4));
}

// ---------------------------------------------------------------- weight transpose f32 -> bf16T
__global__ __launch_bounds__(256) void wtrans(
    const float* __restrict__ W, ushort* __restrict__ Wt, int K, int N) {
    __shared__ float tb[32][33];
    const int tid = threadIdx.x, tx = tid & 31, ty = tid >> 5;
    const size_t zo = (size_t)blockIdx.z * K * N;
    const int k0 = blockIdx.x * 32, n0 = blockIdx.y * 32;
#pragma unroll
    for (int p = 0; p < 4; ++p)
        tb[ty + 8 * p][tx] = W[zo + (size_t)(k0 + ty + 8 * p) * N + n0 + tx];
    __syncthreads();
#pragma unroll
    for (int p = 0; p < 4; ++p)
        Wt[zo + (size_t)(n0 + ty + 8 * p) * K + k0 + tx] = f2bf(tb[tx][ty + 8 * p]);
}

// ---------------------------------------------------------------- f32 -> bf16 cast
__global__ __launch_bounds__(256) void castbf(
    const float* __restrict__ in, ushort* __restrict__ out) {
    const size_t i = ((size_t)blockIdx.x * 256 + threadIdx.x) * 4;
    float4 v = *(const float4*)(in + i);
    ushort4 o = { f2bf(v.x), f2bf(v.y), f2bf(v.z), f2bf(v.w) };
    *(ushort4*)(out + i) = o;
}

// ---------------------------------------------------------------- embed additive part
// x[row][d] = b_rew[d] + E_act[a][d] + r*W_rew[d] + E_time[ti][d]  (4 rows/block)
__global__ __launch_bounds__(256) void embed_add(
    const int* __restrict__ act, const float* __restrict__ rew,
    const int* __restrict__ sobs, const float* __restrict__ E_act,
    const float* __restrict__ W_rew, const float* __restrict__ b_rew,
    const float* __restrict__ E_time, float* __restrict__ x) {
    const int tid = threadIdx.x, lane = tid & 63, w = tid >> 6;
    const int row = blockIdx.x * 4 + w;
    const int b = row >> 9, t = row & 511;
    const int a = act[row];
    const float r = rew[row];
    const int ti = sobs[b] + t;
    const float4* ea = (const float4*)(E_act + (size_t)a * D_);
    const float4* et = (const float4*)(E_time + (size_t)ti * D_);
    const float4* wr4 = (const float4*)W_rew;
    const float4* br4 = (const float4*)b_rew;
    float4* xp = (float4*)(x + (size_t)row * D_);
#pragma unroll
    for (int q = 0; q < 2; ++q) {
        const int i = lane + 64 * q;
        float4 va = ea[i], vt = et[i], vw = wr4[i], vb = br4[i];
        float4 o = { vb.x + va.x + r * vw.x + vt.x,
                     vb.y + va.y + r * vw.y + vt.y,
                     vb.z + va.z + r * vw.z + vt.z,
                     vb.w + va.w + r * vw.w + vt.w };
        xp[i] = o;
    }
}

// ---------------------------------------------------------------- LN -> bf16 (4 rows/block)
__global__ __launch_bounds__(256) void ln_bf16_kernel(
    const float* __restrict__ x, const float* __restrict__ s,
    const float* __restrict__ b, ushort* __restrict__ o) {
    const int tid = threadIdx.x, lane = tid & 63, w = tid >> 6;
    const int row = blockIdx.x * 4 + w;
    const float4* p = (const float4*)(x + (size_t)row * D_);
    float4 a = p[lane], c = p[lane + 64];
    float sm = a.x + a.y + a.z + a.w + c.x + c.y + c.z + c.w;
    float sq = a.x*a.x + a.y*a.y + a.z*a.z + a.w*a.w
             + c.x*c.x + c.y*c.y + c.z*c.z + c.w*c.w;
    sm = wave_sum(sm);
    sq = wave_sum(sq);
    const float mean = sm * (1.0f / 512.0f);
    const float var = sq * (1.0f / 512.0f) - mean * mean;
    const float ri = rsqrtf(var + 1e-6f);
    const float4* s4 = (const float4*)s;
    const float4* b4 = (const float4*)b;
    float4 s1 = s4[lane], b1 = b4[lane];
    ushort4 o1 = { f2bf((a.x - mean) * ri * s1.x + b1.x),
                   f2bf((a.y - mean) * ri * s1.y + b1.y),
                   f2bf((a.z - mean) * ri * s1.z + b1.z),
                   f2bf((a.w - mean) * ri * s1.w + b1.w) };
    *(ushort4*)(o + (size_t)row * D_ + lane * 4) = o1;
    float4 s2 = s4[lane + 64], b2 = b4[lane + 64];
    ushort4 o2 = { f2bf((c.x - mean) * ri * s2.x + b2.x),
                   f2bf((c.y - mean) * ri * s2.y + b2.y),
                   f2bf((c.z - mean) * ri * s2.z + b2.z),
                   f2bf((c.w - mean) * ri * s2.w + b2.w) };
    *(ushort4*)(o + (size_t)row * D_ + (lane + 64) * 4) = o2;
}

// ---------------------------------------------------------------- m97-structure MFMA GEMM
// 128x128 tile, BK=64, global_load_lds(16B) into linear [128][64] LDS,
// 2-barrier loop. C = op(A @ Wt^T + bias); RES: f32 +=, else bf16 store.
template <bool GELU, bool RES>
__global__ __launch_bounds__(256) void gemm_lds(
    const ushort* __restrict__ A, int lda,
    const ushort* __restrict__ Wt,
    const float* __restrict__ bias,
    float* __restrict__ Cf, ushort* __restrict__ Cb, int ldc,
    int K) {
    __shared__ ushort As[128 * 64];
    __shared__ ushort Bs[128 * 64];
    const int tid = threadIdx.x, lane = tid & 63, wid = tid >> 6;
    const int wr = wid >> 1, wc = wid & 1;
    const int lr = lane & 15, lg = lane >> 4;
    const int row0 = blockIdx.y * 128, col0 = blockIdx.x * 128;

    f32x4 zero = {0.f, 0.f, 0.f, 0.f};
    f32x4 acc[4][4];
#pragma unroll
    for (int i = 0; i < 4; ++i)
#pragma unroll
        for (int j = 0; j < 4; ++j) acc[i][j] = zero;

    const ushort* Ag = A + (size_t)row0 * lda;
    const ushort* Bg = Wt + (size_t)col0 * K;

    for (int k0 = 0; k0 < K; k0 += 64) {
        // stage: 4 chunks/thread per matrix; chunk cid covers LDS bytes
        // [cid*16, cid*16+16) = linear element cid*8 -> row cid>>3, col (cid&7)*8
#pragma unroll
        for (int p = 0; p < 4; ++p) {
            const int cid = tid + 256 * p;
            const int r = cid >> 3, c = (cid & 7) * 8;
            GLOAD16(Ag + (size_t)r * lda + k0 + c, &As[cid * 8]);
            GLOAD16(Bg + (size_t)r * K + k0 + c, &Bs[cid * 8]);
        }
        __syncthreads();   // compiler drains vmcnt before s_barrier
#pragma unroll
        for (int kk = 0; kk < 2; ++kk) {
            short8 af[4], bf[4];
#pragma unroll
            for (int i = 0; i < 4; ++i)
                af[i] = *(const short8*)&As[(64 * wr + 16 * i + lr) * 64 + kk * 32 + lg * 8];
#pragma unroll
            for (int j = 0; j < 4; ++j)
                bf[j] = *(const short8*)&Bs[(64 * wc + 16 * j + lr) * 64 + kk * 32 + lg * 8];
#pragma unroll
            for (int i = 0; i < 4; ++i)
#pragma unroll
                for (int j = 0; j < 4; ++j) acc[i][j] = MFMA16(af[i], bf[j], acc[i][j]);
        }
        __syncthreads();   // readers done before next stage overwrites
    }

#pragma unroll
    for (int j = 0; j < 4; ++j) {
        const int col = col0 + 64 * wc + 16 * j + lr;
        const float bj = bias[col];
#pragma unroll
        for (int i = 0; i < 4; ++i) {
            const int rbase = row0 + 64 * wr + 16 * i + lg * 4;
#pragma unroll
            for (int r = 0; r < 4; ++r) {
                float v = acc[i][j][r] + bj;
                if (GELU) v = gelu_tanh(v);
                if (RES) {
                    float* p = Cf + (size_t)(rbase + r) * ldc + col;
                    *p = *p + v;
                } else {
                    Cb[(size_t)(rbase + r) * ldc + col] = f2bf(v);
                }
            }
        }
    }
}

// ---------------------------------------------------------------- MFMA linear attention
// per (b,h): 8 tiles of 64: out = tril(QK^T)V + Q*S_run; S_run += K^T V.
// S kept f32 in regs; out written bf16 over dead q-slice. (unchanged R4)
__global__ __launch_bounds__(256) void attn_bf16(
    ushort* __restrict__ qkv, const float* __restrict__ sin_,
    float* __restrict__ sout, int layer, int b0) {
    __shared__ ushort Qs[4096], Ks[4096], Kt[4096], Vt[4096], Ps[4096], Stb[4096];
    const int tid = threadIdx.x, lane = tid & 63, w = tid >> 6;
    const int lr = lane & 15, lg = lane >> 4;
    const int bh = blockIdx.x, bl = bh >> 3, h = bh & 7;
    const size_t soff = (((size_t)(b0 + bl) * L_ + layer) * H_ + h) * 4096;

    f32x4 zero = {0.f, 0.f, 0.f, 0.f};
    f32x4 stacc[4];
#pragma unroll
    for (int n = 0; n < 4; ++n)
#pragma unroll
        for (int r = 0; r < 4; ++r)
            stacc[n][r] = sin_[soff + (size_t)(16 * n + lr) * 64 + 16 * w + lg * 4 + r];

    const int st = tid >> 3, sd8 = (tid & 7) * 8;

    for (int tile = 0; tile < 8; ++tile) {
        const int t0 = tile * 64;
#pragma unroll
        for (int p = 0; p < 2; ++p) {
            const int t = st + 32 * p;
            const ushort* g = qkv + (size_t)(bl * T_ + t0 + t) * 1536 + h * 64;
            short8 q8 = *(const short8*)(g + sd8);
            short8 k8 = *(const short8*)(g + 512 + sd8);
            short8 v8 = *(const short8*)(g + 1024 + sd8);
            *(short8*)((char*)Qs + sw(t, sd8 * 2)) = q8;
            *(short8*)((char*)Ks + sw(t, sd8 * 2)) = k8;
#pragma unroll
            for (int j = 0; j < 8; ++j) {
                *(ushort*)((char*)Kt + sw(sd8 + j, t * 2)) = (ushort)k8[j];
                *(ushort*)((char*)Vt + sw(sd8 + j, t * 2)) = (ushort)v8[j];
            }
        }
#pragma unroll
        for (int n = 0; n < 4; ++n)
#pragma unroll
            for (int r = 0; r < 4; ++r)
                *(ushort*)((char*)Stb + sw(16 * w + lg * 4 + r, (16 * n + lr) * 2)) =
                    f2bf(stacc[n][r]);
        __syncthreads();

        short8 aq[2];
#pragma unroll
        for (int k2 = 0; k2 < 2; ++k2)
            aq[k2] = *(const short8*)((char*)Qs + sw(16 * w + lr, k2 * 64 + lg * 16));

        f32x4 pacc[4], oacc[4];
#pragma unroll
        for (int n = 0; n < 4; ++n) { pacc[n] = zero; oacc[n] = zero; }
#pragma unroll
        for (int k2 = 0; k2 < 2; ++k2)
#pragma unroll
            for (int n = 0; n < 4; ++n) {
                short8 bk = *(const short8*)((char*)Ks + sw(16 * n + lr, k2 * 64 + lg * 16));
                pacc[n] = MFMA16(aq[k2], bk, pacc[n]);
            }
#pragma unroll
        for (int k2 = 0; k2 < 2; ++k2)
#pragma unroll
            for (int n = 0; n < 4; ++n) {
                short8 bs = *(const short8*)((char*)Stb + sw(16 * n + lr, k2 * 64 + lg * 16));
                oacc[n] = MFMA16(aq[k2], bs, oacc[n]);
            }
        // causal mask within tile; P -> bf16 LDS
#pragma unroll
        for (int n = 0; n < 4; ++n)
#pragma unroll
            for (int r = 0; r < 4; ++r) {
                const int t = 16 * w + lg * 4 + r, s = 16 * n + lr;
                *(ushort*)((char*)Ps + sw(t, s * 2)) =
                    (s <= t) ? f2bf(pacc[n][r]) : (ushort)0;
            }
        short8 ap[2], av[2];
#pragma unroll
        for (int k2 = 0; k2 < 2; ++k2) {
            ap[k2] = *(const short8*)((char*)Ps + sw(16 * w + lr, k2 * 64 + lg * 16));
            av[k2] = *(const short8*)((char*)Vt + sw(16 * w + lr, k2 * 64 + lg * 16));
        }
#pragma unroll
        for (int k2 = 0; k2 < 2; ++k2)
#pragma unroll
            for (int n = 0; n < 4; ++n) {
                short8 bv = *(const short8*)((char*)Vt + sw(16 * n + lr, k2 * 64 + lg * 16));
                oacc[n] = MFMA16(ap[k2], bv, oacc[n]);
            }
#pragma unroll
        for (int k2 = 0; k2 < 2; ++k2)
#pragma unroll
            for (int n = 0; n < 4; ++n) {
                short8 bkt = *(const short8*)((char*)Kt + sw(16 * n + lr, k2 * 64 + lg * 16));
                stacc[n] = MFMA16(av[k2], bkt, stacc[n]);
            }
#pragma unroll
        for (int n = 0; n < 4; ++n)
#pragma unroll
            for (int r = 0; r < 4; ++r) {
                const int t = 16 * w + lg * 4 + r, e = 16 * n + lr;
                qkv[(size_t)(bl * T_ + t0 + t) * 1536 + h * 64 + e] = f2bf(oacc[n][r]);
            }
        __syncthreads();
    }
#pragma unroll
    for (int n = 0; n < 4; ++n)
#pragma unroll
        for (int r = 0; r < 4; ++r)
            sout[soff + (size_t)(16 * n + lr) * 64 + 16 * w + lg * 4 + r] = stacc[n][r];
}

// ---------------------------------------------------------------- final LN + heads (4 rows/block)
__global__ __launch_bounds__(256) void head_kernel(
    const float* __restrict__ x, const float* __restrict__ lnf_s,
    const float* __restrict__ lnf_b, const float* __restrict__ W_actor,
    const float* __restrict__ b_actor, const float* __restrict__ W_critic,
    const float* __restrict__ b_critic, float* __restrict__ logits,
    float* __restrict__ val) {
    __shared__ float nb[4][512];
    const int tid = threadIdx.x, lane = tid & 63, w = tid >> 6;
    const int row = blockIdx.x * 4 + w;
    const float4* p = (const float4*)(x + (size_t)row * D_);
    float4 a = p[lane], c = p[lane + 64];
    float sm = a.x + a.y + a.z + a.w + c.x + c.y + c.z + c.w;
    float sq = a.x*a.x + a.y*a.y + a.z*a.z + a.w*a.w
             + c.x*c.x + c.y*c.y + c.z*c.z + c.w*c.w;
    sm = wave_sum(sm);
    sq = wave_sum(sq);
    const float mean = sm * (1.0f / 512.0f);
    const float var = sq * (1.0f / 512.0f) - mean * mean;
    const float ri = rsqrtf(var + 1e-6f);
    const float4* s4 = (const float4*)lnf_s;
    const float4* b4 = (const float4*)lnf_b;
    float4 s1 = s4[lane], b1 = b4[lane];
    float4 s2 = s4[lane + 64], b2 = b4[lane + 64];
    float4 n1 = { (a.x - mean) * ri * s1.x + b1.x, (a.y - mean) * ri * s1.y + b1.y,
                  (a.z - mean) * ri * s1.z + b1.z, (a.w - mean) * ri * s1.w + b1.w };
    float4 n2 = { (c.x - mean) * ri * s2.x + b2.x, (c.y - mean) * ri * s2.y + b2.y,
                  (c.z - mean) * ri * s2.z + b2.z, (c.w - mean) * ri * s2.w + b2.w };
    *(float4*)&nb[w][lane * 4] = n1;
    *(float4*)&nb[w][(lane + 64) * 4] = n2;

    float pj[16];
#pragma unroll
    for (int j = 0; j < 16; ++j) pj[j] = 0.0f;
    float pv = 0.0f;
#pragma unroll
    for (int it = 0; it < 8; ++it) {
        const int d = lane + 64 * it;
        const float nv = nb[w][d];
        const float4* wa = (const float4*)(W_actor + d * NACT);
        float4 w0 = wa[0], w1 = wa[1], w2 = wa[2], w3 = wa[3];
        pj[0] = fmaf(nv, w0.x, pj[0]);  pj[1] = fmaf(nv, w0.y, pj[1]);
        pj[2] = fmaf(nv, w0.z, pj[2]);  pj[3] = fmaf(nv, w0.w, pj[3]);
        pj[4] = fmaf(nv, w1.x, pj[4]);  pj[5] = fmaf(nv, w1.y, pj[5]);
        pj[6] = fmaf(nv, w1.z, pj[6]);  pj[7] = fmaf(nv, w1.w, pj[7]);
        pj[8] = fmaf(nv, w2.x, pj[8]);  pj[9] = fmaf(nv, w2.y, pj[9]);
        pj[10] = fmaf(nv, w2.z, pj[10]); pj[11] = fmaf(nv, w2.w, pj[11]);
        pj[12] = fmaf(nv, w3.x, pj[12]); pj[13] = fmaf(nv, w3.y, pj[13]);
        pj[14] = fmaf(nv, w3.z, pj[14]); pj[15] = fmaf(nv, w3.w, pj[15]);
        pv = fmaf(nv, W_critic[d], pv);
    }
#pragma unroll
    for (int j = 0; j < 16; ++j) pj[j] = wave_sum(pj[j]);
    pv = wave_sum(pv);
    if (lane == 0) {
#pragma unroll
        for (int j = 0; j < 16; ++j) logits[(size_t)row * NACT + j] = pj[j] + b_actor[j];
        val[row] = pv + b_critic[0];
    }
}

__global__ void sobs_kernel(const int* __restrict__ sobs, float* __restrict__ out) {
    const int i = threadIdx.x;
    if (i < B_) out[i] = (float)(sobs[i] + T_);
}

// ---------------------------------------------------------------- launch
extern "C" void kernel_launch(void* const* d_in, const int* in_sizes, int n_in,
                              void* d_out, int out_size, void* d_ws, size_t ws_size,
                              hipStream_t stream) {
    const float* obs     = (const float*)d_in[0];
    const int*   act_p   = (const int*)d_in[1];
    const float* rew_p   = (const float*)d_in[2];
    const int*   sobs    = (const int*)d_in[3];
    const float* sblk    = (const float*)d_in[4];
    const float* W_obs   = (const float*)d_in[5];
    const float* b_obs   = (const float*)d_in[6];
    const float* E_act   = (const float*)d_in[7];
    const float* W_rew   = (const float*)d_in[8];
    const float* b_rew   = (const float*)d_in[9];
    const float* E_time  = (const float*)d_in[10];
    const float* ln1_s   = (const float*)d_in[11];
    const float* ln1_b   = (const float*)d_in[12];
    const float* Wqkv    = (const float*)d_in[13];
    const float* bqkv    = (const float*)d_in[14];
    const float* Wout    = (const float*)d_in[15];
    const float* bout    = (const float*)d_in[16];
    const float* ln2_s   = (const float*)d_in[17];
    const float* ln2_b   = (const float*)d_in[18];
    const float* W1      = (const float*)d_in[19];
    const float* b1      = (const float*)d_in[20];
    const float* W2      = (const float*)d_in[21];
    const float* b2      = (const float*)d_in[22];
    const float* lnf_s   = (const float*)d_in[23];
    const float* lnf_b   = (const float*)d_in[24];
    const float* W_actor = (const float*)d_in[25];
    const float* b_actor = (const float*)d_in[26];
    const float* W_crit  = (const float*)d_in[27];
    const float* b_crit  = (const float*)d_in[28];

    float* out        = (float*)d_out;
    float* out_blocks = out;
    float* out_sobs   = out + (size_t)B_ * L_ * H_ * 64 * 64;
    float* out_logits = out_sobs + B_;
    float* out_val    = out_logits + (size_t)ROWS * NACT;

    float*  x    = (float*)d_ws;                        // ROWS*512 f32   (64 MB)
    ushort* h    = (ushort*)(x + (size_t)ROWS * D_);    // CH_ROWS*512    (8 MB)
    ushort* big  = h + (size_t)CH_ROWS * D_;            // CH_ROWS*2048   (32 MB)
    ushort* wq   = big + (size_t)CH_ROWS * DFF;         // 4*512*1536     (6 MB)
    ushort* wo   = wq + (size_t)L_ * D_ * 3 * D_;       // 4*512*512      (2 MB)
    ushort* w1t  = wo + (size_t)L_ * D_ * D_;           // 4*512*2048     (8 MB)
    ushort* w2t  = w1t + (size_t)L_ * D_ * DFF;         // 4*2048*512     (8 MB)
    ushort* obsb = w2t + (size_t)L_ * DFF * D_;         // ROWS*64        (4 MB)
    ushort* wob  = obsb + (size_t)ROWS * 64;            // 512*64         (64 KB)
    const size_t need = (size_t)ROWS * D_ * 4 + (size_t)CH_ROWS * D_ * 2
                      + (size_t)CH_ROWS * DFF * 2
                      + ((size_t)L_ * (D_ * 3 * D_ + D_ * D_ + 2 * D_ * DFF)) * 2
                      + (size_t)ROWS * 64 * 2 + (size_t)D_ * 64 * 2;
    if (ws_size < need) return;  // fail soft

    wtrans<<<dim3(16, 48, L_), 256, 0, stream>>>(Wqkv, wq, D_, 3 * D_);
    wtrans<<<dim3(16, 16, L_), 256, 0, stream>>>(Wout, wo, D_, D_);
    wtrans<<<dim3(16, 64, L_), 256, 0, stream>>>(W1, w1t, D_, DFF);
    wtrans<<<dim3(64, 16, L_), 256, 0, stream>>>(W2, w2t, DFF, D_);
    wtrans<<<dim3(2, 16, 1), 256, 0, stream>>>(W_obs, wob, 64, D_);
    castbf<<<ROWS * 64 / 1024, 256, 0, stream>>>(obs, obsb);

    // embed = gather part + MFMA obs@W_obs (RES accumulate, bias=b_obs)
    embed_add<<<ROWS / 4, 256, 0, stream>>>(act_p, rew_p, sobs, E_act, W_rew,
                                            b_rew, E_time, x);
    gemm_lds<false, true><<<dim3(4, 256), 256, 0, stream>>>(
        obsb, 64, wob, b_obs, x, nullptr, D_, 64);

    for (int l = 0; l < L_; ++l) {
        for (int rc = 0; rc < RC_; ++rc) {
            const size_t ro = (size_t)rc * CH_ROWS;
            ln_bf16_kernel<<<CH_ROWS / 4, 256, 0, stream>>>(
                x + ro * D_, ln1_s + l * D_, ln1_b + l * D_, h);
            gemm_lds<false, false><<<dim3(12, 64), 256, 0, stream>>>(
                h, D_, wq + (size_t)l * D_ * 3 * D_, bqkv + l * 3 * D_,
                nullptr, big, 3 * D_, D_);
            attn_bf16<<<CH_B * H_, 256, 0, stream>>>(big, sblk, out_blocks, l, rc * CH_B);
            gemm_lds<false, true><<<dim3(4, 64), 256, 0, stream>>>(
                big, 3 * D_, wo + (size_t)l * D_ * D_, bout + l * D_,
                x + ro * D_, nullptr, D_, D_);
            ln_bf16_kernel<<<CH_ROWS / 4, 256, 0, stream>>>(
                x + ro * D_, ln2_s + l * D_, ln2_b + l * D_, h);
            gemm_lds<true, false><<<dim3(16, 64), 256, 0, stream>>>(
                h, D_, w1t + (size_t)l * D_ * DFF, b1 + l * DFF,
                nullptr, big, DFF, D_);
            gemm_lds<false, true><<<dim3(4, 64), 256, 0, stream>>>(
                big, DFF, w2t + (size_t)l * DFF * D_, b2 + l * D_,
                x + ro * D_, nullptr, D_, DFF);
        }
    }
    head_kernel<<<ROWS / 4, 256, 0, stream>>>(x, lnf_s, lnf_b, W_actor, b_actor,
                                              W_crit, b_crit, out_logits, out_val);
    sobs_kernel<<<1, 64, 0, stream>>>(sobs, out_sobs);
}

// Round 8
// 2765.450 us; speedup vs baseline: 1.2180x; 1.2180x over previous
//
#include <hip/hip_runtime.h>
#include <hip/hip_bf16.h>
#include <math.h>

// LinearTransformerAgent R8 (= R7 resubmit; R7 bench was a broker timeout).
// Reg-staged GEMM (R4 structure) + BN-templated tile (outproj/W2 at 128x64),
// fast GELU, embed as gather + MFMA obs GEMM. attn/ln/head unchanged.
// ws 132.2 MB.

#define B_    64
#define T_    512
#define D_    512
#define H_    8
#define L_    4
#define NACT  16
#define DFF   2048
#define ROWS  (B_ * T_)
#define RC_   4
#define CH_ROWS (ROWS / RC_)     // 8192
#define CH_B  (B_ / RC_)         // 16

typedef __attribute__((ext_vector_type(8))) short short8;
typedef __attribute__((ext_vector_type(4))) float f32x4;
#define MFMA16(a, b, c) __builtin_amdgcn_mfma_f32_16x16x32_bf16(a, b, c, 0, 0, 0)

__device__ __forceinline__ ushort f2bf(float f) {
    union { float f; unsigned u; } c; c.f = f;
    unsigned r = c.u + 0x7FFF + ((c.u >> 16) & 1);
    return (ushort)(r >> 16);
}
// gelu(v) = 0.5 v (1+tanh(u)) = v - v/(1+e^{2u})
__device__ __forceinline__ float gelu_tanh(float v) {
    float u = 0.7978845608028654f * (v + 0.044715f * v * v * v);
    return v - v / (1.0f + __expf(2.0f * u));
}
__device__ __forceinline__ float wave_sum(float v) {
#pragma unroll
    for (int o = 32; o > 0; o >>= 1) v += __shfl_xor(v, o);
    return v;
}
// XOR-swizzled byte offset into a [rows][128B] LDS tile
__device__ __forceinline__ int sw(int row, int kb) {
    return row * 128 + (kb ^ ((row & 7) << 4));
}

// ---------------------------------------------------------------- weight transpose f32 -> bf16T
__global__ __launch_bounds__(256) void wtrans(
    const float* __restrict__ W, ushort* __restrict__ Wt, int K, int N) {
    __shared__ float tb[32][33];
    const int tid = threadIdx.x, tx = tid & 31, ty = tid >> 5;
    const size_t zo = (size_t)blockIdx.z * K * N;
    const int k0 = blockIdx.x * 32, n0 = blockIdx.y * 32;
#pragma unroll
    for (int p = 0; p < 4; ++p)
        tb[ty + 8 * p][tx] = W[zo + (size_t)(k0 + ty + 8 * p) * N + n0 + tx];
    __syncthreads();
#pragma unroll
    for (int p = 0; p < 4; ++p)
        Wt[zo + (size_t)(n0 + ty + 8 * p) * K + k0 + tx] = f2bf(tb[tx][ty + 8 * p]);
}

// ---------------------------------------------------------------- f32 -> bf16 cast
__global__ __launch_bounds__(256) void castbf(
    const float* __restrict__ in, ushort* __restrict__ out) {
    const size_t i = ((size_t)blockIdx.x * 256 + threadIdx.x) * 4;
    float4 v = *(const float4*)(in + i);
    ushort4 o = { f2bf(v.x), f2bf(v.y), f2bf(v.z), f2bf(v.w) };
    *(ushort4*)(out + i) = o;
}

// ---------------------------------------------------------------- embed additive part
__global__ __launch_bounds__(256) void embed_add(
    const int* __restrict__ act, const float* __restrict__ rew,
    const int* __restrict__ sobs, const float* __restrict__ E_act,
    const float* __restrict__ W_rew, const float* __restrict__ b_rew,
    const float* __restrict__ E_time, float* __restrict__ x) {
    const int tid = threadIdx.x, lane = tid & 63, w = tid >> 6;
    const int row = blockIdx.x * 4 + w;
    const int b = row >> 9, t = row & 511;
    const int a = act[row];
    const float r = rew[row];
    const int ti = sobs[b] + t;
    const float4* ea = (const float4*)(E_act + (size_t)a * D_);
    const float4* et = (const float4*)(E_time + (size_t)ti * D_);
    const float4* wr4 = (const float4*)W_rew;
    const float4* br4 = (const float4*)b_rew;
    float4* xp = (float4*)(x + (size_t)row * D_);
#pragma unroll
    for (int q = 0; q < 2; ++q) {
        const int i = lane + 64 * q;
        float4 va = ea[i], vt = et[i], vw = wr4[i], vb = br4[i];
        float4 o = { vb.x + va.x + r * vw.x + vt.x,
                     vb.y + va.y + r * vw.y + vt.y,
                     vb.z + va.z + r * vw.z + vt.z,
                     vb.w + va.w + r * vw.w + vt.w };
        xp[i] = o;
    }
}

// ---------------------------------------------------------------- LN -> bf16 (4 rows/block)
__global__ __launch_bounds__(256) void ln_bf16_kernel(
    const float* __restrict__ x, const float* __restrict__ s,
    const float* __restrict__ b, ushort* __restrict__ o) {
    const int tid = threadIdx.x, lane = tid & 63, w = tid >> 6;
    const int row = blockIdx.x * 4 + w;
    const float4* p = (const float4*)(x + (size_t)row * D_);
    float4 a = p[lane], c = p[lane + 64];
    float sm = a.x + a.y + a.z + a.w + c.x + c.y + c.z + c.w;
    float sq = a.x*a.x + a.y*a.y + a.z*a.z + a.w*a.w
             + c.x*c.x + c.y*c.y + c.z*c.z + c.w*c.w;
    sm = wave_sum(sm);
    sq = wave_sum(sq);
    const float mean = sm * (1.0f / 512.0f);
    const float var = sq * (1.0f / 512.0f) - mean * mean;
    const float ri = rsqrtf(var + 1e-6f);
    const float4* s4 = (const float4*)s;
    const float4* b4 = (const float4*)b;
    float4 s1 = s4[lane], b1 = b4[lane];
    ushort4 o1 = { f2bf((a.x - mean) * ri * s1.x + b1.x),
                   f2bf((a.y - mean) * ri * s1.y + b1.y),
                   f2bf((a.z - mean) * ri * s1.z + b1.z),
                   f2bf((a.w - mean) * ri * s1.w + b1.w) };
    *(ushort4*)(o + (size_t)row * D_ + lane * 4) = o1;
    float4 s2 = s4[lane + 64], b2 = b4[lane + 64];
    ushort4 o2 = { f2bf((c.x - mean) * ri * s2.x + b2.x),
                   f2bf((c.y - mean) * ri * s2.y + b2.y),
                   f2bf((c.z - mean) * ri * s2.z + b2.z),
                   f2bf((c.w - mean) * ri * s2.w + b2.w) };
    *(ushort4*)(o + (size_t)row * D_ + (lane + 64) * 4) = o2;
}

// ---------------------------------------------------------------- reg-staged MFMA GEMM
// 128xBN tile, BK=64, reg prefetch -> swizzled LDS, 2-barrier loop.
// C = op(A[M,K] @ Wt[N,K]^T + bias); RES: f32 +=, else bf16 store.
template <int BN, bool GELU, bool RES>
__global__ __launch_bounds__(256) void gemm_rs(
    const ushort* __restrict__ A, int lda,
    const ushort* __restrict__ Wt,
    const float* __restrict__ bias,
    float* __restrict__ Cf, ushort* __restrict__ Cb, int ldc,
    int K) {
    constexpr int NJ = BN / 32;          // 16-col frags per wave
    __shared__ ushort As[128 * 64];
    __shared__ ushort Bs[BN * 64];
    const int tid = threadIdx.x, lane = tid & 63, wid = tid >> 6;
    const int wr = wid >> 1, wc = wid & 1;
    const int lr = lane & 15, lg = lane >> 4;
    const int row0 = blockIdx.y * 128, col0 = blockIdx.x * BN;

    f32x4 zero = {0.f, 0.f, 0.f, 0.f};
    f32x4 acc[4][NJ];
#pragma unroll
    for (int i = 0; i < 4; ++i)
#pragma unroll
        for (int j = 0; j < NJ; ++j) acc[i][j] = zero;

    const int smb = tid >> 3, sk = (tid & 7) * 8;   // 8 lanes x 16B per row
    const ushort* Ap = A + (size_t)(row0 + smb) * lda + sk;
    const ushort* Bp = Wt + (size_t)(col0 + smb) * K + sk;
    const int soff = smb * 128 + ((sk * 2) ^ ((smb & 7) << 4));

    short8 ra[4], rb[NJ];
#pragma unroll
    for (int p = 0; p < 4; ++p) ra[p] = *(const short8*)(Ap + (size_t)(32 * p) * lda);
#pragma unroll
    for (int p = 0; p < NJ; ++p) rb[p] = *(const short8*)(Bp + (size_t)(32 * p) * K);

    for (int k0 = 0;;) {
        __syncthreads();
#pragma unroll
        for (int p = 0; p < 4; ++p) *(short8*)((char*)As + soff + p * 4096) = ra[p];
#pragma unroll
        for (int p = 0; p < NJ; ++p) *(short8*)((char*)Bs + soff + p * 4096) = rb[p];
        __syncthreads();
        k0 += 64;
        if (k0 < K) {
#pragma unroll
            for (int p = 0; p < 4; ++p)
                ra[p] = *(const short8*)(Ap + (size_t)(32 * p) * lda + k0);
#pragma unroll
            for (int p = 0; p < NJ; ++p)
                rb[p] = *(const short8*)(Bp + (size_t)(32 * p) * K + k0);
        }
#pragma unroll
        for (int k2 = 0; k2 < 2; ++k2) {
            short8 af[4], bf[NJ];
#pragma unroll
            for (int i = 0; i < 4; ++i)
                af[i] = *(const short8*)((char*)As + sw(64 * wr + 16 * i + lr, k2 * 64 + lg * 16));
#pragma unroll
            for (int j = 0; j < NJ; ++j)
                bf[j] = *(const short8*)((char*)Bs + sw((BN / 2) * wc + 16 * j + lr, k2 * 64 + lg * 16));
#pragma unroll
            for (int i = 0; i < 4; ++i)
#pragma unroll
                for (int j = 0; j < NJ; ++j) acc[i][j] = MFMA16(af[i], bf[j], acc[i][j]);
        }
        if (k0 >= K) break;
    }

#pragma unroll
    for (int j = 0; j < NJ; ++j) {
        const int col = col0 + (BN / 2) * wc + 16 * j + lr;
        const float bj = bias[col];
#pragma unroll
        for (int i = 0; i < 4; ++i) {
            const int rbase = row0 + 64 * wr + 16 * i + lg * 4;
#pragma unroll
            for (int r = 0; r < 4; ++r) {
                float v = acc[i][j][r] + bj;
                if (GELU) v = gelu_tanh(v);
                if (RES) {
                    float* p = Cf + (size_t)(rbase + r) * ldc + col;
                    *p = *p + v;
                } else {
                    Cb[(size_t)(rbase + r) * ldc + col] = f2bf(v);
                }
            }
        }
    }
}

// ---------------------------------------------------------------- MFMA linear attention
// per (b,h): 8 tiles of 64: out = tril(QK^T)V + Q*S_run; S_run += K^T V.
__global__ __launch_bounds__(256) void attn_bf16(
    ushort* __restrict__ qkv, const float* __restrict__ sin_,
    float* __restrict__ sout, int layer, int b0) {
    __shared__ ushort Qs[4096], Ks[4096], Kt[4096], Vt[4096], Ps[4096], Stb[4096];
    const int tid = threadIdx.x, lane = tid & 63, w = tid >> 6;
    const int lr = lane & 15, lg = lane >> 4;
    const int bh = blockIdx.x, bl = bh >> 3, h = bh & 7;
    const size_t soff = (((size_t)(b0 + bl) * L_ + layer) * H_ + h) * 4096;

    f32x4 zero = {0.f, 0.f, 0.f, 0.f};
    f32x4 stacc[4];
#pragma unroll
    for (int n = 0; n < 4; ++n)
#pragma unroll
        for (int r = 0; r < 4; ++r)
            stacc[n][r] = sin_[soff + (size_t)(16 * n + lr) * 64 + 16 * w + lg * 4 + r];

    const int st = tid >> 3, sd8 = (tid & 7) * 8;

    for (int tile = 0; tile < 8; ++tile) {
        const int t0 = tile * 64;
#pragma unroll
        for (int p = 0; p < 2; ++p) {
            const int t = st + 32 * p;
            const ushort* g = qkv + (size_t)(bl * T_ + t0 + t) * 1536 + h * 64;
            short8 q8 = *(const short8*)(g + sd8);
            short8 k8 = *(const short8*)(g + 512 + sd8);
            short8 v8 = *(const short8*)(g + 1024 + sd8);
            *(short8*)((char*)Qs + sw(t, sd8 * 2)) = q8;
            *(short8*)((char*)Ks + sw(t, sd8 * 2)) = k8;
#pragma unroll
            for (int j = 0; j < 8; ++j) {
                *(ushort*)((char*)Kt + sw(sd8 + j, t * 2)) = (ushort)k8[j];
                *(ushort*)((char*)Vt + sw(sd8 + j, t * 2)) = (ushort)v8[j];
            }
        }
#pragma unroll
        for (int n = 0; n < 4; ++n)
#pragma unroll
            for (int r = 0; r < 4; ++r)
                *(ushort*)((char*)Stb + sw(16 * w + lg * 4 + r, (16 * n + lr) * 2)) =
                    f2bf(stacc[n][r]);
        __syncthreads();

        short8 aq[2];
#pragma unroll
        for (int k2 = 0; k2 < 2; ++k2)
            aq[k2] = *(const short8*)((char*)Qs + sw(16 * w + lr, k2 * 64 + lg * 16));

        f32x4 pacc[4], oacc[4];
#pragma unroll
        for (int n = 0; n < 4; ++n) { pacc[n] = zero; oacc[n] = zero; }
#pragma unroll
        for (int k2 = 0; k2 < 2; ++k2)
#pragma unroll
            for (int n = 0; n < 4; ++n) {
                short8 bk = *(const short8*)((char*)Ks + sw(16 * n + lr, k2 * 64 + lg * 16));
                pacc[n] = MFMA16(aq[k2], bk, pacc[n]);
            }
#pragma unroll
        for (int k2 = 0; k2 < 2; ++k2)
#pragma unroll
            for (int n = 0; n < 4; ++n) {
                short8 bs = *(const short8*)((char*)Stb + sw(16 * n + lr, k2 * 64 + lg * 16));
                oacc[n] = MFMA16(aq[k2], bs, oacc[n]);
            }
#pragma unroll
        for (int n = 0; n < 4; ++n)
#pragma unroll
            for (int r = 0; r < 4; ++r) {
                const int t = 16 * w + lg * 4 + r, s = 16 * n + lr;
                *(ushort*)((char*)Ps + sw(t, s * 2)) =
                    (s <= t) ? f2bf(pacc[n][r]) : (ushort)0;
            }
        short8 ap[2], av[2];
#pragma unroll
        for (int k2 = 0; k2 < 2; ++k2) {
            ap[k2] = *(const short8*)((char*)Ps + sw(16 * w + lr, k2 * 64 + lg * 16));
            av[k2] = *(const short8*)((char*)Vt + sw(16 * w + lr, k2 * 64 + lg * 16));
        }
#pragma unroll
        for (int k2 = 0; k2 < 2; ++k2)
#pragma unroll
            for (int n = 0; n < 4; ++n) {
                short8 bv = *(const short8*)((char*)Vt + sw(16 * n + lr, k2 * 64 + lg * 16));
                oacc[n] = MFMA16(ap[k2], bv, oacc[n]);
            }
#pragma unroll
        for (int k2 = 0; k2 < 2; ++k2)
#pragma unroll
            for (int n = 0; n < 4; ++n) {
                short8 bkt = *(const short8*)((char*)Kt + sw(16 * n + lr, k2 * 64 + lg * 16));
                stacc[n] = MFMA16(av[k2], bkt, stacc[n]);
            }
#pragma unroll
        for (int n = 0; n < 4; ++n)
#pragma unroll
            for (int r = 0; r < 4; ++r) {
                const int t = 16 * w + lg * 4 + r, e = 16 * n + lr;
                qkv[(size_t)(bl * T_ + t0 + t) * 1536 + h * 64 + e] = f2bf(oacc[n][r]);
            }
        __syncthreads();
    }
#pragma unroll
    for (int n = 0; n < 4; ++n)
#pragma unroll
        for (int r = 0; r < 4; ++r)
            sout[soff + (size_t)(16 * n + lr) * 64 + 16 * w + lg * 4 + r] = stacc[n][r];
}

// ---------------------------------------------------------------- final LN + heads (4 rows/block)
__global__ __launch_bounds__(256) void head_kernel(
    const float* __restrict__ x, const float* __restrict__ lnf_s,
    const float* __restrict__ lnf_b, const float* __restrict__ W_actor,
    const float* __restrict__ b_actor, const float* __restrict__ W_critic,
    const float* __restrict__ b_critic, float* __restrict__ logits,
    float* __restrict__ val) {
    __shared__ float nb[4][512];
    const int tid = threadIdx.x, lane = tid & 63, w = tid >> 6;
    const int row = blockIdx.x * 4 + w;
    const float4* p = (const float4*)(x + (size_t)row * D_);
    float4 a = p[lane], c = p[lane + 64];
    float sm = a.x + a.y + a.z + a.w + c.x + c.y + c.z + c.w;
    float sq = a.x*a.x + a.y*a.y + a.z*a.z + a.w*a.w
             + c.x*c.x + c.y*c.y + c.z*c.z + c.w*c.w;
    sm = wave_sum(sm);
    sq = wave_sum(sq);
    const float mean = sm * (1.0f / 512.0f);
    const float var = sq * (1.0f / 512.0f) - mean * mean;
    const float ri = rsqrtf(var + 1e-6f);
    const float4* s4 = (const float4*)lnf_s;
    const float4* b4 = (const float4*)lnf_b;
    float4 s1 = s4[lane], b1 = b4[lane];
    float4 s2 = s4[lane + 64], b2 = b4[lane + 64];
    float4 n1 = { (a.x - mean) * ri * s1.x + b1.x, (a.y - mean) * ri * s1.y + b1.y,
                  (a.z - mean) * ri * s1.z + b1.z, (a.w - mean) * ri * s1.w + b1.w };
    float4 n2 = { (c.x - mean) * ri * s2.x + b2.x, (c.y - mean) * ri * s2.y + b2.y,
                  (c.z - mean) * ri * s2.z + b2.z, (c.w - mean) * ri * s2.w + b2.w };
    *(float4*)&nb[w][lane * 4] = n1;
    *(float4*)&nb[w][(lane + 64) * 4] = n2;

    float pj[16];
#pragma unroll
    for (int j = 0; j < 16; ++j) pj[j] = 0.0f;
    float pv = 0.0f;
#pragma unroll
    for (int it = 0; it < 8; ++it) {
        const int d = lane + 64 * it;
        const float nv = nb[w][d];
        const float4* wa = (const float4*)(W_actor + d * NACT);
        float4 w0 = wa[0], w1 = wa[1], w2 = wa[2], w3 = wa[3];
        pj[0] = fmaf(nv, w0.x, pj[0]);  pj[1] = fmaf(nv, w0.y, pj[1]);
        pj[2] = fmaf(nv, w0.z, pj[2]);  pj[3] = fmaf(nv, w0.w, pj[3]);
        pj[4] = fmaf(nv, w1.x, pj[4]);  pj[5] = fmaf(nv, w1.y, pj[5]);
        pj[6] = fmaf(nv, w1.z, pj[6]);  pj[7] = fmaf(nv, w1.w, pj[7]);
        pj[8] = fmaf(nv, w2.x, pj[8]);  pj[9] = fmaf(nv, w2.y, pj[9]);
        pj[10] = fmaf(nv, w2.z, pj[10]); pj[11] = fmaf(nv, w2.w, pj[11]);
        pj[12] = fmaf(nv, w3.x, pj[12]); pj[13] = fmaf(nv, w3.y, pj[13]);
        pj[14] = fmaf(nv, w3.z, pj[14]); pj[15] = fmaf(nv, w3.w, pj[15]);
        pv = fmaf(nv, W_critic[d], pv);
    }
#pragma unroll
    for (int j = 0; j < 16; ++j) pj[j] = wave_sum(pj[j]);
    pv = wave_sum(pv);
    if (lane == 0) {
#pragma unroll
        for (int j = 0; j < 16; ++j) logits[(size_t)row * NACT + j] = pj[j] + b_actor[j];
        val[row] = pv + b_critic[0];
    }
}

__global__ void sobs_kernel(const int* __restrict__ sobs, float* __restrict__ out) {
    const int i = threadIdx.x;
    if (i < B_) out[i] = (float)(sobs[i] + T_);
}

// ---------------------------------------------------------------- launch
extern "C" void kernel_launch(void* const* d_in, const int* in_sizes, int n_in,
                              void* d_out, int out_size, void* d_ws, size_t ws_size,
                              hipStream_t stream) {
    const float* obs     = (const float*)d_in[0];
    const int*   act_p   = (const int*)d_in[1];
    const float* rew_p   = (const float*)d_in[2];
    const int*   sobs    = (const int*)d_in[3];
    const float* sblk    = (const float*)d_in[4];
    const float* W_obs   = (const float*)d_in[5];
    const float* b_obs   = (const float*)d_in[6];
    const float* E_act   = (const float*)d_in[7];
    const float* W_rew   = (const float*)d_in[8];
    const float* b_rew   = (const float*)d_in[9];
    const float* E_time  = (const float*)d_in[10];
    const float* ln1_s   = (const float*)d_in[11];
    const float* ln1_b   = (const float*)d_in[12];
    const float* Wqkv    = (const float*)d_in[13];
    const float* bqkv    = (const float*)d_in[14];
    const float* Wout    = (const float*)d_in[15];
    const float* bout    = (const float*)d_in[16];
    const float* ln2_s   = (const float*)d_in[17];
    const float* ln2_b   = (const float*)d_in[18];
    const float* W1      = (const float*)d_in[19];
    const float* b1      = (const float*)d_in[20];
    const float* W2      = (const float*)d_in[21];
    const float* b2      = (const float*)d_in[22];
    const float* lnf_s   = (const float*)d_in[23];
    const float* lnf_b   = (const float*)d_in[24];
    const float* W_actor = (const float*)d_in[25];
    const float* b_actor = (const float*)d_in[26];
    const float* W_crit  = (const float*)d_in[27];
    const float* b_crit  = (const float*)d_in[28];

    float* out        = (float*)d_out;
    float* out_blocks = out;
    float* out_sobs   = out + (size_t)B_ * L_ * H_ * 64 * 64;
    float* out_logits = out_sobs + B_;
    float* out_val    = out_logits + (size_t)ROWS * NACT;

    float*  x    = (float*)d_ws;                        // ROWS*512 f32   (64 MB)
    ushort* h    = (ushort*)(x + (size_t)ROWS * D_);    // CH_ROWS*512    (8 MB)
    ushort* big  = h + (size_t)CH_ROWS * D_;            // CH_ROWS*2048   (32 MB)
    ushort* wq   = big + (size_t)CH_ROWS * DFF;         // 4*512*1536     (6 MB)
    ushort* wo   = wq + (size_t)L_ * D_ * 3 * D_;       // 4*512*512      (2 MB)
    ushort* w1t  = wo + (size_t)L_ * D_ * D_;           // 4*512*2048     (8 MB)
    ushort* w2t  = w1t + (size_t)L_ * D_ * DFF;         // 4*2048*512     (8 MB)
    ushort* obsb = w2t + (size_t)L_ * DFF * D_;         // ROWS*64        (4 MB)
    ushort* wob  = obsb + (size_t)ROWS * 64;            // 512*64         (64 KB)
    const size_t need = (size_t)ROWS * D_ * 4 + (size_t)CH_ROWS * D_ * 2
                      + (size_t)CH_ROWS * DFF * 2
                      + ((size_t)L_ * (D_ * 3 * D_ + D_ * D_ + 2 * D_ * DFF)) * 2
                      + (size_t)ROWS * 64 * 2 + (size_t)D_ * 64 * 2;
    if (ws_size < need) return;  // fail soft

    wtrans<<<dim3(16, 48, L_), 256, 0, stream>>>(Wqkv, wq, D_, 3 * D_);
    wtrans<<<dim3(16, 16, L_), 256, 0, stream>>>(Wout, wo, D_, D_);
    wtrans<<<dim3(16, 64, L_), 256, 0, stream>>>(W1, w1t, D_, DFF);
    wtrans<<<dim3(64, 16, L_), 256, 0, stream>>>(W2, w2t, DFF, D_);
    wtrans<<<dim3(2, 16, 1), 256, 0, stream>>>(W_obs, wob, 64, D_);
    castbf<<<ROWS * 64 / 1024, 256, 0, stream>>>(obs, obsb);

    // embed = gather part + MFMA obs@W_obs (RES accumulate, bias=b_obs)
    embed_add<<<ROWS / 4, 256, 0, stream>>>(act_p, rew_p, sobs, E_act, W_rew,
                                            b_rew, E_time, x);
    gemm_rs<128, false, true><<<dim3(4, 256), 256, 0, stream>>>(
        obsb, 64, wob, b_obs, x, nullptr, D_, 64);

    for (int l = 0; l < L_; ++l) {
        for (int rc = 0; rc < RC_; ++rc) {
            const size_t ro = (size_t)rc * CH_ROWS;
            ln_bf16_kernel<<<CH_ROWS / 4, 256, 0, stream>>>(
                x + ro * D_, ln1_s + l * D_, ln1_b + l * D_, h);
            gemm_rs<128, false, false><<<dim3(12, 64), 256, 0, stream>>>(
                h, D_, wq + (size_t)l * D_ * 3 * D_, bqkv + l * 3 * D_,
                nullptr, big, 3 * D_, D_);
            attn_bf16<<<CH_B * H_, 256, 0, stream>>>(big, sblk, out_blocks, l, rc * CH_B);
            gemm_rs<64, false, true><<<dim3(8, 64), 256, 0, stream>>>(
                big, 3 * D_, wo + (size_t)l * D_ * D_, bout + l * D_,
                x + ro * D_, nullptr, D_, D_);
            ln_bf16_kernel<<<CH_ROWS / 4, 256, 0, stream>>>(
                x + ro * D_, ln2_s + l * D_, ln2_b + l * D_, h);
            gemm_rs<128, true, false><<<dim3(16, 64), 256, 0, stream>>>(
                h, D_, w1t + (size_t)l * D_ * DFF, b1 + l * DFF,
                nullptr, big, DFF, D_);
            gemm_rs<64, false, true><<<dim3(8, 64), 256, 0, stream>>>(
                big, DFF, w2t + (size_t)l * DFF * D_, b2 + l * D_,
                x + ro * D_, nullptr, D_, DFF);
        }
    }
    head_kernel<<<ROWS / 4, 256, 0, stream>>>(x, lnf_s, lnf_b, W_actor, b_actor,
                                              W_crit, b_crit, out_logits, out_val);
    sobs_kernel<<<1, 64, 0, stream>>>(sobs, out_sobs);
}

// Round 9
// 2379.068 us; speedup vs baseline: 1.4158x; 1.1624x over previous
//
#include <hip/hip_runtime.h>
#include <hip/hip_bf16.h>
#include <math.h>

// LinearTransformerAgent R9: R8 + (1) XCD-aware block swizzle in all GEMMs,
// (2) head via lnf+MFMA GEMM (packed W_actor||W_critic), (3) attn T14
// async-stage (reg prefetch of next tile during compute).
// ws 132.3 MB.

#define B_    64
#define T_    512
#define D_    512
#define H_    8
#define L_    4
#define NACT  16
#define DFF   2048
#define ROWS  (B_ * T_)
#define RC_   4
#define CH_ROWS (ROWS / RC_)     // 8192
#define CH_B  (B_ / RC_)         // 16

typedef __attribute__((ext_vector_type(8))) short short8;
typedef __attribute__((ext_vector_type(4))) float f32x4;
#define MFMA16(a, b, c) __builtin_amdgcn_mfma_f32_16x16x32_bf16(a, b, c, 0, 0, 0)

__device__ __forceinline__ ushort f2bf(float f) {
    union { float f; unsigned u; } c; c.f = f;
    unsigned r = c.u + 0x7FFF + ((c.u >> 16) & 1);
    return (ushort)(r >> 16);
}
// gelu(v) = 0.5 v (1+tanh(u)) = v - v/(1+e^{2u})
__device__ __forceinline__ float gelu_tanh(float v) {
    float u = 0.7978845608028654f * (v + 0.044715f * v * v * v);
    return v - v / (1.0f + __expf(2.0f * u));
}
__device__ __forceinline__ float wave_sum(float v) {
#pragma unroll
    for (int o = 32; o > 0; o >>= 1) v += __shfl_xor(v, o);
    return v;
}
// XOR-swizzled byte offset into a [rows][128B] LDS tile
__device__ __forceinline__ int sw(int row, int kb) {
    return row * 128 + (kb ^ ((row & 7) << 4));
}

// ---------------------------------------------------------------- weight transpose f32 -> bf16T
__global__ __launch_bounds__(256) void wtrans(
    const float* __restrict__ W, ushort* __restrict__ Wt, int K, int N) {
    __shared__ float tb[32][33];
    const int tid = threadIdx.x, tx = tid & 31, ty = tid >> 5;
    const size_t zo = (size_t)blockIdx.z * K * N;
    const int k0 = blockIdx.x * 32, n0 = blockIdx.y * 32;
#pragma unroll
    for (int p = 0; p < 4; ++p)
        tb[ty + 8 * p][tx] = W[zo + (size_t)(k0 + ty + 8 * p) * N + n0 + tx];
    __syncthreads();
#pragma unroll
    for (int p = 0; p < 4; ++p)
        Wt[zo + (size_t)(n0 + ty + 8 * p) * K + k0 + tx] = f2bf(tb[tx][ty + 8 * p]);
}

// ---------------------------------------------------------------- f32 -> bf16 cast
__global__ __launch_bounds__(256) void castbf(
    const float* __restrict__ in, ushort* __restrict__ out) {
    const size_t i = ((size_t)blockIdx.x * 256 + threadIdx.x) * 4;
    float4 v = *(const float4*)(in + i);
    ushort4 o = { f2bf(v.x), f2bf(v.y), f2bf(v.z), f2bf(v.w) };
    *(ushort4*)(out + i) = o;
}

// ---------------------------------------------------------------- head weight pack
// wh[n][k] (bf16, n<16: W_actor^T, n==16: W_critic, else 0); whb[n] bias
__global__ void headprep(const float* __restrict__ Wa, const float* __restrict__ ba,
                         const float* __restrict__ Wc, const float* __restrict__ bc,
                         ushort* __restrict__ wh, float* __restrict__ whb) {
    const int n = blockIdx.x, k = threadIdx.x;
    float v = (n < 16) ? Wa[(size_t)k * NACT + n] : (n == 16 ? Wc[k] : 0.0f);
    wh[(size_t)n * D_ + k] = f2bf(v);
    if (k == 0) whb[n] = (n < 16) ? ba[n] : (n == 16 ? bc[0] : 0.0f);
}

// ---------------------------------------------------------------- head output split
__global__ __launch_bounds__(256) void headsplit(
    const float* __restrict__ tmp, float* __restrict__ logits, float* __restrict__ val) {
    const size_t idx = (size_t)blockIdx.x * 256 + threadIdx.x;  // ROWS*16
    const size_t row = idx >> 4;
    const int j = (int)(idx & 15);
    logits[idx] = tmp[row * 32 + j];
    if (j == 0) val[row] = tmp[row * 32 + 16];
}

// ---------------------------------------------------------------- embed additive part
__global__ __launch_bounds__(256) void embed_add(
    const int* __restrict__ act, const float* __restrict__ rew,
    const int* __restrict__ sobs, const float* __restrict__ E_act,
    const float* __restrict__ W_rew, const float* __restrict__ b_rew,
    const float* __restrict__ E_time, float* __restrict__ x) {
    const int tid = threadIdx.x, lane = tid & 63, w = tid >> 6;
    const int row = blockIdx.x * 4 + w;
    const int b = row >> 9, t = row & 511;
    const int a = act[row];
    const float r = rew[row];
    const int ti = sobs[b] + t;
    const float4* ea = (const float4*)(E_act + (size_t)a * D_);
    const float4* et = (const float4*)(E_time + (size_t)ti * D_);
    const float4* wr4 = (const float4*)W_rew;
    const float4* br4 = (const float4*)b_rew;
    float4* xp = (float4*)(x + (size_t)row * D_);
#pragma unroll
    for (int q = 0; q < 2; ++q) {
        const int i = lane + 64 * q;
        float4 va = ea[i], vt = et[i], vw = wr4[i], vb = br4[i];
        float4 o = { vb.x + va.x + r * vw.x + vt.x,
                     vb.y + va.y + r * vw.y + vt.y,
                     vb.z + va.z + r * vw.z + vt.z,
                     vb.w + va.w + r * vw.w + vt.w };
        xp[i] = o;
    }
}

// ---------------------------------------------------------------- LN -> bf16 (4 rows/block)
__global__ __launch_bounds__(256) void ln_bf16_kernel(
    const float* __restrict__ x, const float* __restrict__ s,
    const float* __restrict__ b, ushort* __restrict__ o) {
    const int tid = threadIdx.x, lane = tid & 63, w = tid >> 6;
    const int row = blockIdx.x * 4 + w;
    const float4* p = (const float4*)(x + (size_t)row * D_);
    float4 a = p[lane], c = p[lane + 64];
    float sm = a.x + a.y + a.z + a.w + c.x + c.y + c.z + c.w;
    float sq = a.x*a.x + a.y*a.y + a.z*a.z + a.w*a.w
             + c.x*c.x + c.y*c.y + c.z*c.z + c.w*c.w;
    sm = wave_sum(sm);
    sq = wave_sum(sq);
    const float mean = sm * (1.0f / 512.0f);
    const float var = sq * (1.0f / 512.0f) - mean * mean;
    const float ri = rsqrtf(var + 1e-6f);
    const float4* s4 = (const float4*)s;
    const float4* b4 = (const float4*)b;
    float4 s1 = s4[lane], b1 = b4[lane];
    ushort4 o1 = { f2bf((a.x - mean) * ri * s1.x + b1.x),
                   f2bf((a.y - mean) * ri * s1.y + b1.y),
                   f2bf((a.z - mean) * ri * s1.z + b1.z),
                   f2bf((a.w - mean) * ri * s1.w + b1.w) };
    *(ushort4*)(o + (size_t)row * D_ + lane * 4) = o1;
    float4 s2 = s4[lane + 64], b2 = b4[lane + 64];
    ushort4 o2 = { f2bf((c.x - mean) * ri * s2.x + b2.x),
                   f2bf((c.y - mean) * ri * s2.y + b2.y),
                   f2bf((c.z - mean) * ri * s2.z + b2.z),
                   f2bf((c.w - mean) * ri * s2.w + b2.w) };
    *(ushort4*)(o + (size_t)row * D_ + (lane + 64) * 4) = o2;
}

// ---------------------------------------------------------------- reg-staged MFMA GEMM
// 128xBN tile, BK=64, reg prefetch -> swizzled LDS, 2-barrier loop.
// XCD-aware block swizzle (nwg % 8 == 0 for all launches).
// C = op(A[M,K] @ Wt[N,K]^T + bias); RES: f32 +=; F32ST: f32 store; else bf16.
template <int BN, bool GELU, bool RES, bool F32ST>
__global__ __launch_bounds__(256) void gemm_rs(
    const ushort* __restrict__ A, int lda,
    const ushort* __restrict__ Wt,
    const float* __restrict__ bias,
    float* __restrict__ Cf, ushort* __restrict__ Cb, int ldc,
    int K) {
    constexpr int NJ = BN / 32;          // 16-col frags per wave
    __shared__ ushort As[128 * 64];
    __shared__ ushort Bs[BN * 64];
    const int tid = threadIdx.x, lane = tid & 63, wid = tid >> 6;
    const int wr = wid >> 1, wc = wid & 1;
    const int lr = lane & 15, lg = lane >> 4;

    // XCD swizzle: contiguous runs of linear ids land on one XCD
    const int nx = gridDim.x;
    int lin = blockIdx.y * nx + blockIdx.x;
    const int qq = (nx * gridDim.y) >> 3;
    lin = (lin & 7) * qq + (lin >> 3);
    const int row0 = (lin / nx) * 128, col0 = (lin % nx) * BN;

    f32x4 zero = {0.f, 0.f, 0.f, 0.f};
    f32x4 acc[4][NJ];
#pragma unroll
    for (int i = 0; i < 4; ++i)
#pragma unroll
        for (int j = 0; j < NJ; ++j) acc[i][j] = zero;

    const int smb = tid >> 3, sk = (tid & 7) * 8;   // 8 lanes x 16B per row
    const ushort* Ap = A + (size_t)(row0 + smb) * lda + sk;
    const ushort* Bp = Wt + (size_t)(col0 + smb) * K + sk;
    const int soff = smb * 128 + ((sk * 2) ^ ((smb & 7) << 4));

    short8 ra[4], rb[NJ];
#pragma unroll
    for (int p = 0; p < 4; ++p) ra[p] = *(const short8*)(Ap + (size_t)(32 * p) * lda);
#pragma unroll
    for (int p = 0; p < NJ; ++p) rb[p] = *(const short8*)(Bp + (size_t)(32 * p) * K);

    for (int k0 = 0;;) {
        __syncthreads();
#pragma unroll
        for (int p = 0; p < 4; ++p) *(short8*)((char*)As + soff + p * 4096) = ra[p];
#pragma unroll
        for (int p = 0; p < NJ; ++p) *(short8*)((char*)Bs + soff + p * 4096) = rb[p];
        __syncthreads();
        k0 += 64;
        if (k0 < K) {
#pragma unroll
            for (int p = 0; p < 4; ++p)
                ra[p] = *(const short8*)(Ap + (size_t)(32 * p) * lda + k0);
#pragma unroll
            for (int p = 0; p < NJ; ++p)
                rb[p] = *(const short8*)(Bp + (size_t)(32 * p) * K + k0);
        }
#pragma unroll
        for (int k2 = 0; k2 < 2; ++k2) {
            short8 af[4], bf[NJ];
#pragma unroll
            for (int i = 0; i < 4; ++i)
                af[i] = *(const short8*)((char*)As + sw(64 * wr + 16 * i + lr, k2 * 64 + lg * 16));
#pragma unroll
            for (int j = 0; j < NJ; ++j)
                bf[j] = *(const short8*)((char*)Bs + sw((BN / 2) * wc + 16 * j + lr, k2 * 64 + lg * 16));
#pragma unroll
            for (int i = 0; i < 4; ++i)
#pragma unroll
                for (int j = 0; j < NJ; ++j) acc[i][j] = MFMA16(af[i], bf[j], acc[i][j]);
        }
        if (k0 >= K) break;
    }

#pragma unroll
    for (int j = 0; j < NJ; ++j) {
        const int col = col0 + (BN / 2) * wc + 16 * j + lr;
        const float bj = bias[col];
#pragma unroll
        for (int i = 0; i < 4; ++i) {
            const int rbase = row0 + 64 * wr + 16 * i + lg * 4;
#pragma unroll
            for (int r = 0; r < 4; ++r) {
                float v = acc[i][j][r] + bj;
                if (GELU) v = gelu_tanh(v);
                if (RES) {
                    float* p = Cf + (size_t)(rbase + r) * ldc + col;
                    *p = *p + v;
                } else if (F32ST) {
                    Cf[(size_t)(rbase + r) * ldc + col] = v;
                } else {
                    Cb[(size_t)(rbase + r) * ldc + col] = f2bf(v);
                }
            }
        }
    }
}

// ---------------------------------------------------------------- MFMA linear attention
// per (b,h): 8 tiles of 64: out = tril(QK^T)V + Q*S_run; S_run += K^T V.
// T14: next tile's q/k/v loaded to regs during compute, written next iter.
__global__ __launch_bounds__(256) void attn_bf16(
    ushort* __restrict__ qkv, const float* __restrict__ sin_,
    float* __restrict__ sout, int layer, int b0) {
    __shared__ ushort Qs[4096], Ks[4096], Kt[4096], Vt[4096], Ps[4096], Stb[4096];
    const int tid = threadIdx.x, lane = tid & 63, w = tid >> 6;
    const int lr = lane & 15, lg = lane >> 4;
    const int bh = blockIdx.x, bl = bh >> 3, h = bh & 7;
    const size_t soff = (((size_t)(b0 + bl) * L_ + layer) * H_ + h) * 4096;

    f32x4 zero = {0.f, 0.f, 0.f, 0.f};
    f32x4 stacc[4];
#pragma unroll
    for (int n = 0; n < 4; ++n)
#pragma unroll
        for (int r = 0; r < 4; ++r)
            stacc[n][r] = sin_[soff + (size_t)(16 * n + lr) * 64 + 16 * w + lg * 4 + r];

    const int st = tid >> 3, sd8 = (tid & 7) * 8;

    // prologue: load tile 0 into regs
    short8 rq[2], rk[2], rv[2];
#pragma unroll
    for (int p = 0; p < 2; ++p) {
        const ushort* g = qkv + (size_t)(bl * T_ + st + 32 * p) * 1536 + h * 64;
        rq[p] = *(const short8*)(g + sd8);
        rk[p] = *(const short8*)(g + 512 + sd8);
        rv[p] = *(const short8*)(g + 1024 + sd8);
    }

    for (int tile = 0; tile < 8; ++tile) {
        // write phase: regs (tile) -> LDS
#pragma unroll
        for (int p = 0; p < 2; ++p) {
            const int t = st + 32 * p;
            *(short8*)((char*)Qs + sw(t, sd8 * 2)) = rq[p];
            *(short8*)((char*)Ks + sw(t, sd8 * 2)) = rk[p];
#pragma unroll
            for (int j = 0; j < 8; ++j) {
                *(ushort*)((char*)Kt + sw(sd8 + j, t * 2)) = (ushort)rk[p][j];
                *(ushort*)((char*)Vt + sw(sd8 + j, t * 2)) = (ushort)rv[p][j];
            }
        }
#pragma unroll
        for (int n = 0; n < 4; ++n)
#pragma unroll
            for (int r = 0; r < 4; ++r)
                *(ushort*)((char*)Stb + sw(16 * w + lg * 4 + r, (16 * n + lr) * 2)) =
                    f2bf(stacc[n][r]);
        __syncthreads();

        // issue next-tile loads (overlap with compute below)
        if (tile < 7) {
            const int t1 = (tile + 1) * 64;
#pragma unroll
            for (int p = 0; p < 2; ++p) {
                const ushort* g = qkv + (size_t)(bl * T_ + t1 + st + 32 * p) * 1536 + h * 64;
                rq[p] = *(const short8*)(g + sd8);
                rk[p] = *(const short8*)(g + 512 + sd8);
                rv[p] = *(const short8*)(g + 1024 + sd8);
            }
        }

        short8 aq[2];
#pragma unroll
        for (int k2 = 0; k2 < 2; ++k2)
            aq[k2] = *(const short8*)((char*)Qs + sw(16 * w + lr, k2 * 64 + lg * 16));

        f32x4 pacc[4], oacc[4];
#pragma unroll
        for (int n = 0; n < 4; ++n) { pacc[n] = zero; oacc[n] = zero; }
#pragma unroll
        for (int k2 = 0; k2 < 2; ++k2)
#pragma unroll
            for (int n = 0; n < 4; ++n) {
                short8 bk = *(const short8*)((char*)Ks + sw(16 * n + lr, k2 * 64 + lg * 16));
                pacc[n] = MFMA16(aq[k2], bk, pacc[n]);
            }
#pragma unroll
        for (int k2 = 0; k2 < 2; ++k2)
#pragma unroll
            for (int n = 0; n < 4; ++n) {
                short8 bs = *(const short8*)((char*)Stb + sw(16 * n + lr, k2 * 64 + lg * 16));
                oacc[n] = MFMA16(aq[k2], bs, oacc[n]);
            }
        // causal mask; P -> bf16 LDS (intra-wave band: in-order LDS per wave)
#pragma unroll
        for (int n = 0; n < 4; ++n)
#pragma unroll
            for (int r = 0; r < 4; ++r) {
                const int t = 16 * w + lg * 4 + r, s = 16 * n + lr;
                *(ushort*)((char*)Ps + sw(t, s * 2)) =
                    (s <= t) ? f2bf(pacc[n][r]) : (ushort)0;
            }
        short8 ap[2], av[2];
#pragma unroll
        for (int k2 = 0; k2 < 2; ++k2) {
            ap[k2] = *(const short8*)((char*)Ps + sw(16 * w + lr, k2 * 64 + lg * 16));
            av[k2] = *(const short8*)((char*)Vt + sw(16 * w + lr, k2 * 64 + lg * 16));
        }
#pragma unroll
        for (int k2 = 0; k2 < 2; ++k2)
#pragma unroll
            for (int n = 0; n < 4; ++n) {
                short8 bv = *(const short8*)((char*)Vt + sw(16 * n + lr, k2 * 64 + lg * 16));
                oacc[n] = MFMA16(ap[k2], bv, oacc[n]);
            }
#pragma unroll
        for (int k2 = 0; k2 < 2; ++k2)
#pragma unroll
            for (int n = 0; n < 4; ++n) {
                short8 bkt = *(const short8*)((char*)Kt + sw(16 * n + lr, k2 * 64 + lg * 16));
                stacc[n] = MFMA16(av[k2], bkt, stacc[n]);
            }
#pragma unroll
        for (int n = 0; n < 4; ++n)
#pragma unroll
            for (int r = 0; r < 4; ++r) {
                const int t = 16 * w + lg * 4 + r, e = 16 * n + lr;
                qkv[(size_t)(bl * T_ + tile * 64 + t) * 1536 + h * 64 + e] = f2bf(oacc[n][r]);
            }
        __syncthreads();
    }
#pragma unroll
    for (int n = 0; n < 4; ++n)
#pragma unroll
        for (int r = 0; r < 4; ++r)
            sout[soff + (size_t)(16 * n + lr) * 64 + 16 * w + lg * 4 + r] = stacc[n][r];
}

__global__ void sobs_kernel(const int* __restrict__ sobs, float* __restrict__ out) {
    const int i = threadIdx.x;
    if (i < B_) out[i] = (float)(sobs[i] + T_);
}

// ---------------------------------------------------------------- launch
extern "C" void kernel_launch(void* const* d_in, const int* in_sizes, int n_in,
                              void* d_out, int out_size, void* d_ws, size_t ws_size,
                              hipStream_t stream) {
    const float* obs     = (const float*)d_in[0];
    const int*   act_p   = (const int*)d_in[1];
    const float* rew_p   = (const float*)d_in[2];
    const int*   sobs    = (const int*)d_in[3];
    const float* sblk    = (const float*)d_in[4];
    const float* W_obs   = (const float*)d_in[5];
    const float* b_obs   = (const float*)d_in[6];
    const float* E_act   = (const float*)d_in[7];
    const float* W_rew   = (const float*)d_in[8];
    const float* b_rew   = (const float*)d_in[9];
    const float* E_time  = (const float*)d_in[10];
    const float* ln1_s   = (const float*)d_in[11];
    const float* ln1_b   = (const float*)d_in[12];
    const float* Wqkv    = (const float*)d_in[13];
    const float* bqkv    = (const float*)d_in[14];
    const float* Wout    = (const float*)d_in[15];
    const float* bout    = (const float*)d_in[16];
    const float* ln2_s   = (const float*)d_in[17];
    const float* ln2_b   = (const float*)d_in[18];
    const float* W1      = (const float*)d_in[19];
    const float* b1      = (const float*)d_in[20];
    const float* W2      = (const float*)d_in[21];
    const float* b2      = (const float*)d_in[22];
    const float* lnf_s   = (const float*)d_in[23];
    const float* lnf_b   = (const float*)d_in[24];
    const float* W_actor = (const float*)d_in[25];
    const float* b_actor = (const float*)d_in[26];
    const float* W_crit  = (const float*)d_in[27];
    const float* b_crit  = (const float*)d_in[28];

    float* out        = (float*)d_out;
    float* out_blocks = out;
    float* out_sobs   = out + (size_t)B_ * L_ * H_ * 64 * 64;
    float* out_logits = out_sobs + B_;
    float* out_val    = out_logits + (size_t)ROWS * NACT;

    float*  x    = (float*)d_ws;                        // ROWS*512 f32   (64 MB)
    ushort* h    = (ushort*)(x + (size_t)ROWS * D_);    // CH_ROWS*512    (8 MB)
    ushort* big  = h + (size_t)CH_ROWS * D_;            // CH_ROWS*2048   (32 MB)
    ushort* wq   = big + (size_t)CH_ROWS * DFF;         // 4*512*1536     (6 MB)
    ushort* wo   = wq + (size_t)L_ * D_ * 3 * D_;       // 4*512*512      (2 MB)
    ushort* w1t  = wo + (size_t)L_ * D_ * D_;           // 4*512*2048     (8 MB)
    ushort* w2t  = w1t + (size_t)L_ * D_ * DFF;         // 4*2048*512     (8 MB)
    ushort* obsb = w2t + (size_t)L_ * DFF * D_;         // ROWS*64        (4 MB)
    ushort* wob  = obsb + (size_t)ROWS * 64;            // 512*64         (64 KB)
    ushort* wh   = wob + (size_t)D_ * 64;               // 32*512         (32 KB)
    float*  whb  = (float*)(wh + 32 * D_);              // 32 f32
    float*  htmp = (float*)obsb;                        // ROWS*32 f32 (reuse, 4 MB)
    const size_t need = (size_t)ROWS * D_ * 4 + (size_t)CH_ROWS * D_ * 2
                      + (size_t)CH_ROWS * DFF * 2
                      + ((size_t)L_ * (D_ * 3 * D_ + D_ * D_ + 2 * D_ * DFF)) * 2
                      + (size_t)ROWS * 64 * 2 + (size_t)D_ * 64 * 2
                      + 32 * D_ * 2 + 32 * 4;
    if (ws_size < need) return;  // fail soft

    wtrans<<<dim3(16, 48, L_), 256, 0, stream>>>(Wqkv, wq, D_, 3 * D_);
    wtrans<<<dim3(16, 16, L_), 256, 0, stream>>>(Wout, wo, D_, D_);
    wtrans<<<dim3(16, 64, L_), 256, 0, stream>>>(W1, w1t, D_, DFF);
    wtrans<<<dim3(64, 16, L_), 256, 0, stream>>>(W2, w2t, DFF, D_);
    wtrans<<<dim3(2, 16, 1), 256, 0, stream>>>(W_obs, wob, 64, D_);
    castbf<<<ROWS * 64 / 1024, 256, 0, stream>>>(obs, obsb);
    headprep<<<32, 512, 0, stream>>>(W_actor, b_actor, W_crit, b_crit, wh, whb);

    // embed = gather part + MFMA obs@W_obs (RES accumulate, bias=b_obs)
    embed_add<<<ROWS / 4, 256, 0, stream>>>(act_p, rew_p, sobs, E_act, W_rew,
                                            b_rew, E_time, x);
    gemm_rs<128, false, true, false><<<dim3(4, 256), 256, 0, stream>>>(
        obsb, 64, wob, b_obs, x, nullptr, D_, 64);

    for (int l = 0; l < L_; ++l) {
        for (int rc = 0; rc < RC_; ++rc) {
            const size_t ro = (size_t)rc * CH_ROWS;
            ln_bf16_kernel<<<CH_ROWS / 4, 256, 0, stream>>>(
                x + ro * D_, ln1_s + l * D_, ln1_b + l * D_, h);
            gemm_rs<128, false, false, false><<<dim3(12, 64), 256, 0, stream>>>(
                h, D_, wq + (size_t)l * D_ * 3 * D_, bqkv + l * 3 * D_,
                nullptr, big, 3 * D_, D_);
            attn_bf16<<<CH_B * H_, 256, 0, stream>>>(big, sblk, out_blocks, l, rc * CH_B);
            gemm_rs<64, false, true, false><<<dim3(8, 64), 256, 0, stream>>>(
                big, 3 * D_, wo + (size_t)l * D_ * D_, bout + l * D_,
                x + ro * D_, nullptr, D_, D_);
            ln_bf16_kernel<<<CH_ROWS / 4, 256, 0, stream>>>(
                x + ro * D_, ln2_s + l * D_, ln2_b + l * D_, h);
            gemm_rs<128, true, false, false><<<dim3(16, 64), 256, 0, stream>>>(
                h, D_, w1t + (size_t)l * D_ * DFF, b1 + l * DFF,
                nullptr, big, DFF, D_);
            gemm_rs<64, false, true, false><<<dim3(8, 64), 256, 0, stream>>>(
                big, DFF, w2t + (size_t)l * DFF * D_, b2 + l * D_,
                x + ro * D_, nullptr, D_, DFF);
        }
    }
    // final LN (full rows, bf16 into big) -> MFMA head GEMM -> split
    ln_bf16_kernel<<<ROWS / 4, 256, 0, stream>>>(x, lnf_s, lnf_b, big);
    gemm_rs<32, false, false, true><<<dim3(1, 256), 256, 0, stream>>>(
        big, D_, wh, whb, htmp, nullptr, 32, D_);
    headsplit<<<ROWS * 16 / 256, 256, 0, stream>>>(htmp, out_logits, out_val);
    sobs_kernel<<<1, 64, 0, stream>>>(sobs, out_sobs);
}

// Round 11
// 2190.788 us; speedup vs baseline: 1.5375x; 1.0859x over previous
//
#include <hip/hip_runtime.h>
#include <hip/hip_bf16.h>
#include <math.h>

// LinearTransformerAgent R11 (= R10 resubmit; R10 bench was a broker timeout).
// LN fused into GEMM A-staging (rowstat pre-pass, f32 A-load -> LN -> bf16 in
// regs) + runtime un-chunking (ws evidence: 256 MiB). Kills 33 ln dispatches.

#define B_    64
#define T_    512
#define D_    512
#define H_    8
#define L_    4
#define NACT  16
#define DFF   2048
#define ROWS  (B_ * T_)
#define RC_   4

typedef __attribute__((ext_vector_type(8))) short short8;
typedef __attribute__((ext_vector_type(4))) float f32x4;
#define MFMA16(a, b, c) __builtin_amdgcn_mfma_f32_16x16x32_bf16(a, b, c, 0, 0, 0)

__device__ __forceinline__ ushort f2bf(float f) {
    union { float f; unsigned u; } c; c.f = f;
    unsigned r = c.u + 0x7FFF + ((c.u >> 16) & 1);
    return (ushort)(r >> 16);
}
__device__ __forceinline__ float gelu_tanh(float v) {
    float u = 0.7978845608028654f * (v + 0.044715f * v * v * v);
    return v - v / (1.0f + __expf(2.0f * u));
}
__device__ __forceinline__ float wave_sum(float v) {
#pragma unroll
    for (int o = 32; o > 0; o >>= 1) v += __shfl_xor(v, o);
    return v;
}
// XOR-swizzled byte offset into a [rows][128B] LDS tile
__device__ __forceinline__ int sw(int row, int kb) {
    return row * 128 + (kb ^ ((row & 7) << 4));
}
// LN 8 f32 -> 8 bf16 (packed short8)
__device__ __forceinline__ short8 ln8(const float* xr, float mean, float rstd,
                                      float4 s0, float4 s1, float4 b0, float4 b1) {
    float4 a0 = *(const float4*)xr, a1 = *(const float4*)(xr + 4);
    short8 o;
    o[0] = (short)f2bf((a0.x - mean) * rstd * s0.x + b0.x);
    o[1] = (short)f2bf((a0.y - mean) * rstd * s0.y + b0.y);
    o[2] = (short)f2bf((a0.z - mean) * rstd * s0.z + b0.z);
    o[3] = (short)f2bf((a0.w - mean) * rstd * s0.w + b0.w);
    o[4] = (short)f2bf((a1.x - mean) * rstd * s1.x + b1.x);
    o[5] = (short)f2bf((a1.y - mean) * rstd * s1.y + b1.y);
    o[6] = (short)f2bf((a1.z - mean) * rstd * s1.z + b1.z);
    o[7] = (short)f2bf((a1.w - mean) * rstd * s1.w + b1.w);
    return o;
}

// ---------------------------------------------------------------- weight transpose f32 -> bf16T
__global__ __launch_bounds__(256) void wtrans(
    const float* __restrict__ W, ushort* __restrict__ Wt, int K, int N) {
    __shared__ float tb[32][33];
    const int tid = threadIdx.x, tx = tid & 31, ty = tid >> 5;
    const size_t zo = (size_t)blockIdx.z * K * N;
    const int k0 = blockIdx.x * 32, n0 = blockIdx.y * 32;
#pragma unroll
    for (int p = 0; p < 4; ++p)
        tb[ty + 8 * p][tx] = W[zo + (size_t)(k0 + ty + 8 * p) * N + n0 + tx];
    __syncthreads();
#pragma unroll
    for (int p = 0; p < 4; ++p)
        Wt[zo + (size_t)(n0 + ty + 8 * p) * K + k0 + tx] = f2bf(tb[tx][ty + 8 * p]);
}

// ---------------------------------------------------------------- f32 -> bf16 cast
__global__ __launch_bounds__(256) void castbf(
    const float* __restrict__ in, ushort* __restrict__ out) {
    const size_t i = ((size_t)blockIdx.x * 256 + threadIdx.x) * 4;
    float4 v = *(const float4*)(in + i);
    ushort4 o = { f2bf(v.x), f2bf(v.y), f2bf(v.z), f2bf(v.w) };
    *(ushort4*)(out + i) = o;
}

// ---------------------------------------------------------------- row stats (mean, rstd)
__global__ __launch_bounds__(256) void rowstat(
    const float* __restrict__ x, float* __restrict__ stats) {
    const int w = threadIdx.x >> 6, lane = threadIdx.x & 63;
    const int row = blockIdx.x * 4 + w;
    const float4* p = (const float4*)(x + (size_t)row * D_);
    float4 a = p[lane], b = p[lane + 64];
    float s = a.x + a.y + a.z + a.w + b.x + b.y + b.z + b.w;
    float q = a.x*a.x + a.y*a.y + a.z*a.z + a.w*a.w
            + b.x*b.x + b.y*b.y + b.z*b.z + b.w*b.w;
    s = wave_sum(s);
    q = wave_sum(q);
    if (lane == 0) {
        const float mean = s * (1.0f / 512.0f);
        const float var = q * (1.0f / 512.0f) - mean * mean;
        stats[(size_t)row * 2 + 0] = mean;
        stats[(size_t)row * 2 + 1] = rsqrtf(var + 1e-6f);
    }
}

// ---------------------------------------------------------------- head weight pack
__global__ void headprep(const float* __restrict__ Wa, const float* __restrict__ ba,
                         const float* __restrict__ Wc, const float* __restrict__ bc,
                         ushort* __restrict__ wh, float* __restrict__ whb) {
    const int n = blockIdx.x, k = threadIdx.x;
    float v = (n < 16) ? Wa[(size_t)k * NACT + n] : (n == 16 ? Wc[k] : 0.0f);
    wh[(size_t)n * D_ + k] = f2bf(v);
    if (k == 0) whb[n] = (n < 16) ? ba[n] : (n == 16 ? bc[0] : 0.0f);
}

// ---------------------------------------------------------------- head output split
__global__ __launch_bounds__(256) void headsplit(
    const float* __restrict__ tmp, float* __restrict__ logits, float* __restrict__ val) {
    const size_t idx = (size_t)blockIdx.x * 256 + threadIdx.x;  // ROWS*16
    const size_t row = idx >> 4;
    const int j = (int)(idx & 15);
    logits[idx] = tmp[row * 32 + j];
    if (j == 0) val[row] = tmp[row * 32 + 16];
}

// ---------------------------------------------------------------- embed additive part
__global__ __launch_bounds__(256) void embed_add(
    const int* __restrict__ act, const float* __restrict__ rew,
    const int* __restrict__ sobs, const float* __restrict__ E_act,
    const float* __restrict__ W_rew, const float* __restrict__ b_rew,
    const float* __restrict__ E_time, float* __restrict__ x) {
    const int tid = threadIdx.x, lane = tid & 63, w = tid >> 6;
    const int row = blockIdx.x * 4 + w;
    const int b = row >> 9, t = row & 511;
    const int a = act[row];
    const float r = rew[row];
    const int ti = sobs[b] + t;
    const float4* ea = (const float4*)(E_act + (size_t)a * D_);
    const float4* et = (const float4*)(E_time + (size_t)ti * D_);
    const float4* wr4 = (const float4*)W_rew;
    const float4* br4 = (const float4*)b_rew;
    float4* xp = (float4*)(x + (size_t)row * D_);
#pragma unroll
    for (int q = 0; q < 2; ++q) {
        const int i = lane + 64 * q;
        float4 va = ea[i], vt = et[i], vw = wr4[i], vb = br4[i];
        float4 o = { vb.x + va.x + r * vw.x + vt.x,
                     vb.y + va.y + r * vw.y + vt.y,
                     vb.z + va.z + r * vw.z + vt.z,
                     vb.w + va.w + r * vw.w + vt.w };
        xp[i] = o;
    }
}

// ---------------------------------------------------------------- reg-staged MFMA GEMM
// 128xBN tile, BK=64, reg prefetch -> swizzled LDS, 2-barrier loop, XCD swizzle.
// LNA: A is f32 x, LN applied at staging (stats/lns/lnb). Else A bf16.
// C = op(A @ Wt^T + bias); RES: f32 +=; F32ST: f32 store; else bf16 store.
template <int BN, bool LNA, bool GELU, bool RES, bool F32ST>
__global__ __launch_bounds__(256) void gemm_rs(
    const void* __restrict__ Av, int lda,
    const ushort* __restrict__ Wt,
    const float* __restrict__ bias,
    const float* __restrict__ stats,
    const float* __restrict__ lns, const float* __restrict__ lnb,
    float* __restrict__ Cf, ushort* __restrict__ Cb, int ldc,
    int K) {
    constexpr int NJ = BN / 32;
    __shared__ ushort As[128 * 64];
    __shared__ ushort Bs[BN * 64];
    const int tid = threadIdx.x, lane = tid & 63, wid = tid >> 6;
    const int wr = wid >> 1, wc = wid & 1;
    const int lr = lane & 15, lg = lane >> 4;

    // XCD swizzle (all launches have nwg % 8 == 0)
    const int nx = gridDim.x;
    int lin = blockIdx.y * nx + blockIdx.x;
    const int qq = (nx * gridDim.y) >> 3;
    lin = (lin & 7) * qq + (lin >> 3);
    const int row0 = (lin / nx) * 128, col0 = (lin % nx) * BN;

    f32x4 zero = {0.f, 0.f, 0.f, 0.f};
    f32x4 acc[4][NJ];
#pragma unroll
    for (int i = 0; i < 4; ++i)
#pragma unroll
        for (int j = 0; j < NJ; ++j) acc[i][j] = zero;

    const int smb = tid >> 3, sk = (tid & 7) * 8;
    const int soff = smb * 128 + ((sk * 2) ^ ((smb & 7) << 4));
    const float*  Af = (const float*)Av;
    const ushort* Ab = (const ushort*)Av;
    const ushort* Bp = Wt + (size_t)(col0 + smb) * K + sk;

    float mean_[4], rstd_[4];
    if (LNA) {
#pragma unroll
        for (int p = 0; p < 4; ++p) {
            const int rr = row0 + smb + 32 * p;
            mean_[p] = stats[(size_t)rr * 2 + 0];
            rstd_[p] = stats[(size_t)rr * 2 + 1];
        }
    }

    short8 ra[4], rb[NJ];
    // prologue load (k0 = 0)
    if (LNA) {
        float4 s0 = *(const float4*)(lns + sk), s1 = *(const float4*)(lns + sk + 4);
        float4 b0 = *(const float4*)(lnb + sk), b1 = *(const float4*)(lnb + sk + 4);
#pragma unroll
        for (int p = 0; p < 4; ++p)
            ra[p] = ln8(Af + (size_t)(row0 + smb + 32 * p) * lda + sk,
                        mean_[p], rstd_[p], s0, s1, b0, b1);
    } else {
#pragma unroll
        for (int p = 0; p < 4; ++p)
            ra[p] = *(const short8*)(Ab + (size_t)(row0 + smb + 32 * p) * lda + sk);
    }
#pragma unroll
    for (int p = 0; p < NJ; ++p) rb[p] = *(const short8*)(Bp + (size_t)(32 * p) * K);

    for (int k0 = 0;;) {
        __syncthreads();
#pragma unroll
        for (int p = 0; p < 4; ++p) *(short8*)((char*)As + soff + p * 4096) = ra[p];
#pragma unroll
        for (int p = 0; p < NJ; ++p) *(short8*)((char*)Bs + soff + p * 4096) = rb[p];
        __syncthreads();
        k0 += 64;
        if (k0 < K) {
            if (LNA) {
                float4 s0 = *(const float4*)(lns + k0 + sk);
                float4 s1 = *(const float4*)(lns + k0 + sk + 4);
                float4 b0 = *(const float4*)(lnb + k0 + sk);
                float4 b1 = *(const float4*)(lnb + k0 + sk + 4);
#pragma unroll
                for (int p = 0; p < 4; ++p)
                    ra[p] = ln8(Af + (size_t)(row0 + smb + 32 * p) * lda + k0 + sk,
                                mean_[p], rstd_[p], s0, s1, b0, b1);
            } else {
#pragma unroll
                for (int p = 0; p < 4; ++p)
                    ra[p] = *(const short8*)(Ab + (size_t)(row0 + smb + 32 * p) * lda + k0 + sk);
            }
#pragma unroll
            for (int p = 0; p < NJ; ++p)
                rb[p] = *(const short8*)(Bp + (size_t)(32 * p) * K + k0);
        }
#pragma unroll
        for (int k2 = 0; k2 < 2; ++k2) {
            short8 af[4], bf[NJ];
#pragma unroll
            for (int i = 0; i < 4; ++i)
                af[i] = *(const short8*)((char*)As + sw(64 * wr + 16 * i + lr, k2 * 64 + lg * 16));
#pragma unroll
            for (int j = 0; j < NJ; ++j)
                bf[j] = *(const short8*)((char*)Bs + sw((BN / 2) * wc + 16 * j + lr, k2 * 64 + lg * 16));
#pragma unroll
            for (int i = 0; i < 4; ++i)
#pragma unroll
                for (int j = 0; j < NJ; ++j) acc[i][j] = MFMA16(af[i], bf[j], acc[i][j]);
        }
        if (k0 >= K) break;
    }

#pragma unroll
    for (int j = 0; j < NJ; ++j) {
        const int col = col0 + (BN / 2) * wc + 16 * j + lr;
        const float bj = bias[col];
#pragma unroll
        for (int i = 0; i < 4; ++i) {
            const int rbase = row0 + 64 * wr + 16 * i + lg * 4;
#pragma unroll
            for (int r = 0; r < 4; ++r) {
                float v = acc[i][j][r] + bj;
                if (GELU) v = gelu_tanh(v);
                if (RES) {
                    float* p = Cf + (size_t)(rbase + r) * ldc + col;
                    *p = *p + v;
                } else if (F32ST) {
                    Cf[(size_t)(rbase + r) * ldc + col] = v;
                } else {
                    Cb[(size_t)(rbase + r) * ldc + col] = f2bf(v);
                }
            }
        }
    }
}

// ---------------------------------------------------------------- MFMA linear attention
__global__ __launch_bounds__(256) void attn_bf16(
    ushort* __restrict__ qkv, const float* __restrict__ sin_,
    float* __restrict__ sout, int layer, int b0) {
    __shared__ ushort Qs[4096], Ks[4096], Kt[4096], Vt[4096], Ps[4096], Stb[4096];
    const int tid = threadIdx.x, lane = tid & 63, w = tid >> 6;
    const int lr = lane & 15, lg = lane >> 4;
    const int bh = blockIdx.x, bl = bh >> 3, h = bh & 7;
    const size_t soff = (((size_t)(b0 + bl) * L_ + layer) * H_ + h) * 4096;

    f32x4 zero = {0.f, 0.f, 0.f, 0.f};
    f32x4 stacc[4];
#pragma unroll
    for (int n = 0; n < 4; ++n)
#pragma unroll
        for (int r = 0; r < 4; ++r)
            stacc[n][r] = sin_[soff + (size_t)(16 * n + lr) * 64 + 16 * w + lg * 4 + r];

    const int st = tid >> 3, sd8 = (tid & 7) * 8;

    short8 rq[2], rk[2], rv[2];
#pragma unroll
    for (int p = 0; p < 2; ++p) {
        const ushort* g = qkv + (size_t)(bl * T_ + st + 32 * p) * 1536 + h * 64;
        rq[p] = *(const short8*)(g + sd8);
        rk[p] = *(const short8*)(g + 512 + sd8);
        rv[p] = *(const short8*)(g + 1024 + sd8);
    }

    for (int tile = 0; tile < 8; ++tile) {
#pragma unroll
        for (int p = 0; p < 2; ++p) {
            const int t = st + 32 * p;
            *(short8*)((char*)Qs + sw(t, sd8 * 2)) = rq[p];
            *(short8*)((char*)Ks + sw(t, sd8 * 2)) = rk[p];
#pragma unroll
            for (int j = 0; j < 8; ++j) {
                *(ushort*)((char*)Kt + sw(sd8 + j, t * 2)) = (ushort)rk[p][j];
                *(ushort*)((char*)Vt + sw(sd8 + j, t * 2)) = (ushort)rv[p][j];
            }
        }
#pragma unroll
        for (int n = 0; n < 4; ++n)
#pragma unroll
            for (int r = 0; r < 4; ++r)
                *(ushort*)((char*)Stb + sw(16 * w + lg * 4 + r, (16 * n + lr) * 2)) =
                    f2bf(stacc[n][r]);
        __syncthreads();

        if (tile < 7) {
            const int t1 = (tile + 1) * 64;
#pragma unroll
            for (int p = 0; p < 2; ++p) {
                const ushort* g = qkv + (size_t)(bl * T_ + t1 + st + 32 * p) * 1536 + h * 64;
                rq[p] = *(const short8*)(g + sd8);
                rk[p] = *(const short8*)(g + 512 + sd8);
                rv[p] = *(const short8*)(g + 1024 + sd8);
            }
        }

        short8 aq[2];
#pragma unroll
        for (int k2 = 0; k2 < 2; ++k2)
            aq[k2] = *(const short8*)((char*)Qs + sw(16 * w + lr, k2 * 64 + lg * 16));

        f32x4 pacc[4], oacc[4];
#pragma unroll
        for (int n = 0; n < 4; ++n) { pacc[n] = zero; oacc[n] = zero; }
#pragma unroll
        for (int k2 = 0; k2 < 2; ++k2)
#pragma unroll
            for (int n = 0; n < 4; ++n) {
                short8 bk = *(const short8*)((char*)Ks + sw(16 * n + lr, k2 * 64 + lg * 16));
                pacc[n] = MFMA16(aq[k2], bk, pacc[n]);
            }
#pragma unroll
        for (int k2 = 0; k2 < 2; ++k2)
#pragma unroll
            for (int n = 0; n < 4; ++n) {
                short8 bs = *(const short8*)((char*)Stb + sw(16 * n + lr, k2 * 64 + lg * 16));
                oacc[n] = MFMA16(aq[k2], bs, oacc[n]);
            }
#pragma unroll
        for (int n = 0; n < 4; ++n)
#pragma unroll
            for (int r = 0; r < 4; ++r) {
                const int t = 16 * w + lg * 4 + r, s = 16 * n + lr;
                *(ushort*)((char*)Ps + sw(t, s * 2)) =
                    (s <= t) ? f2bf(pacc[n][r]) : (ushort)0;
            }
        short8 ap[2], av[2];
#pragma unroll
        for (int k2 = 0; k2 < 2; ++k2) {
            ap[k2] = *(const short8*)((char*)Ps + sw(16 * w + lr, k2 * 64 + lg * 16));
            av[k2] = *(const short8*)((char*)Vt + sw(16 * w + lr, k2 * 64 + lg * 16));
        }
#pragma unroll
        for (int k2 = 0; k2 < 2; ++k2)
#pragma unroll
            for (int n = 0; n < 4; ++n) {
                short8 bv = *(const short8*)((char*)Vt + sw(16 * n + lr, k2 * 64 + lg * 16));
                oacc[n] = MFMA16(ap[k2], bv, oacc[n]);
            }
#pragma unroll
        for (int k2 = 0; k2 < 2; ++k2)
#pragma unroll
            for (int n = 0; n < 4; ++n) {
                short8 bkt = *(const short8*)((char*)Kt + sw(16 * n + lr, k2 * 64 + lg * 16));
                stacc[n] = MFMA16(av[k2], bkt, stacc[n]);
            }
#pragma unroll
        for (int n = 0; n < 4; ++n)
#pragma unroll
            for (int r = 0; r < 4; ++r) {
                const int t = 16 * w + lg * 4 + r, e = 16 * n + lr;
                qkv[(size_t)(bl * T_ + tile * 64 + t) * 1536 + h * 64 + e] = f2bf(oacc[n][r]);
            }
        __syncthreads();
    }
#pragma unroll
    for (int n = 0; n < 4; ++n)
#pragma unroll
        for (int r = 0; r < 4; ++r)
            sout[soff + (size_t)(16 * n + lr) * 64 + 16 * w + lg * 4 + r] = stacc[n][r];
}

__global__ void sobs_kernel(const int* __restrict__ sobs, float* __restrict__ out) {
    const int i = threadIdx.x;
    if (i < B_) out[i] = (float)(sobs[i] + T_);
}

// ---------------------------------------------------------------- launch
extern "C" void kernel_launch(void* const* d_in, const int* in_sizes, int n_in,
                              void* d_out, int out_size, void* d_ws, size_t ws_size,
                              hipStream_t stream) {
    const float* obs     = (const float*)d_in[0];
    const int*   act_p   = (const int*)d_in[1];
    const float* rew_p   = (const float*)d_in[2];
    const int*   sobs    = (const int*)d_in[3];
    const float* sblk    = (const float*)d_in[4];
    const float* W_obs   = (const float*)d_in[5];
    const float* b_obs   = (const float*)d_in[6];
    const float* E_act   = (const float*)d_in[7];
    const float* W_rew   = (const float*)d_in[8];
    const float* b_rew   = (const float*)d_in[9];
    const float* E_time  = (const float*)d_in[10];
    const float* ln1_s   = (const float*)d_in[11];
    const float* ln1_b   = (const float*)d_in[12];
    const float* Wqkv    = (const float*)d_in[13];
    const float* bqkv    = (const float*)d_in[14];
    const float* Wout    = (const float*)d_in[15];
    const float* bout    = (const float*)d_in[16];
    const float* ln2_s   = (const float*)d_in[17];
    const float* ln2_b   = (const float*)d_in[18];
    const float* W1      = (const float*)d_in[19];
    const float* b1      = (const float*)d_in[20];
    const float* W2      = (const float*)d_in[21];
    const float* b2      = (const float*)d_in[22];
    const float* lnf_s   = (const float*)d_in[23];
    const float* lnf_b   = (const float*)d_in[24];
    const float* W_actor = (const float*)d_in[25];
    const float* b_actor = (const float*)d_in[26];
    const float* W_crit  = (const float*)d_in[27];
    const float* b_crit  = (const float*)d_in[28];

    float* out        = (float*)d_out;
    float* out_blocks = out;
    float* out_sobs   = out + (size_t)B_ * L_ * H_ * 64 * 64;
    float* out_logits = out_sobs + B_;
    float* out_val    = out_logits + (size_t)ROWS * NACT;

    const size_t wbytes = ((size_t)L_ * (D_ * 3 * D_ + D_ * D_ + 2 * D_ * DFF)) * 2;
    auto need_for = [&](int chrows) {
        return (size_t)ROWS * D_ * 4 + (size_t)chrows * DFF * 2 + wbytes
             + (size_t)ROWS * 64 * 2 + (size_t)D_ * 64 * 2
             + (size_t)32 * D_ * 2 + 32 * 4 + (size_t)ROWS * 2 * 4;
    };
    const int rcn = (ws_size >= need_for(ROWS)) ? 1 : RC_;
    const int chrows = ROWS / rcn, chb = B_ / rcn;
    if (ws_size < need_for(chrows)) return;  // fail soft

    float*  x    = (float*)d_ws;                        // ROWS*512 f32
    ushort* big  = (ushort*)(x + (size_t)ROWS * D_);    // chrows*2048 bf16
    ushort* wq   = big + (size_t)chrows * DFF;
    ushort* wo   = wq + (size_t)L_ * D_ * 3 * D_;
    ushort* w1t  = wo + (size_t)L_ * D_ * D_;
    ushort* w2t  = w1t + (size_t)L_ * D_ * DFF;
    ushort* obsb = w2t + (size_t)L_ * DFF * D_;         // ROWS*64 bf16
    ushort* wob  = obsb + (size_t)ROWS * 64;            // 512*64
    ushort* wh   = wob + (size_t)D_ * 64;               // 32*512
    float*  whb  = (float*)(wh + 32 * D_);              // 32
    float*  stats = whb + 32;                           // ROWS*2 f32
    float*  htmp = (float*)obsb;                        // ROWS*32 f32 (reuse)

    wtrans<<<dim3(16, 48, L_), 256, 0, stream>>>(Wqkv, wq, D_, 3 * D_);
    wtrans<<<dim3(16, 16, L_), 256, 0, stream>>>(Wout, wo, D_, D_);
    wtrans<<<dim3(16, 64, L_), 256, 0, stream>>>(W1, w1t, D_, DFF);
    wtrans<<<dim3(64, 16, L_), 256, 0, stream>>>(W2, w2t, DFF, D_);
    wtrans<<<dim3(2, 16, 1), 256, 0, stream>>>(W_obs, wob, 64, D_);
    castbf<<<ROWS * 64 / 1024, 256, 0, stream>>>(obs, obsb);
    headprep<<<32, 512, 0, stream>>>(W_actor, b_actor, W_crit, b_crit, wh, whb);

    embed_add<<<ROWS / 4, 256, 0, stream>>>(act_p, rew_p, sobs, E_act, W_rew,
                                            b_rew, E_time, x);
    gemm_rs<128, false, false, true, false><<<dim3(4, 256), 256, 0, stream>>>(
        obsb, 64, wob, b_obs, nullptr, nullptr, nullptr, x, nullptr, D_, 64);

    for (int l = 0; l < L_; ++l) {
        for (int rc = 0; rc < rcn; ++rc) {
            const size_t ro = (size_t)rc * chrows;
            rowstat<<<chrows / 4, 256, 0, stream>>>(x + ro * D_, stats + ro * 2);
            gemm_rs<128, true, false, false, false><<<dim3(12, chrows / 128), 256, 0, stream>>>(
                x + ro * D_, D_, wq + (size_t)l * D_ * 3 * D_, bqkv + l * 3 * D_,
                stats + ro * 2, ln1_s + l * D_, ln1_b + l * D_,
                nullptr, big, 3 * D_, D_);
            attn_bf16<<<chb * H_, 256, 0, stream>>>(big, sblk, out_blocks, l, rc * chb);
            gemm_rs<64, false, false, true, false><<<dim3(8, chrows / 128), 256, 0, stream>>>(
                big, 3 * D_, wo + (size_t)l * D_ * D_, bout + l * D_,
                nullptr, nullptr, nullptr, x + ro * D_, nullptr, D_, D_);
            rowstat<<<chrows / 4, 256, 0, stream>>>(x + ro * D_, stats + ro * 2);
            gemm_rs<128, true, true, false, false><<<dim3(16, chrows / 128), 256, 0, stream>>>(
                x + ro * D_, D_, w1t + (size_t)l * D_ * DFF, b1 + l * DFF,
                stats + ro * 2, ln2_s + l * D_, ln2_b + l * D_,
                nullptr, big, DFF, D_);
            gemm_rs<64, false, false, true, false><<<dim3(8, chrows / 128), 256, 0, stream>>>(
                big, DFF, w2t + (size_t)l * DFF * D_, b2 + l * D_,
                nullptr, nullptr, nullptr, x + ro * D_, nullptr, D_, DFF);
        }
    }
    // final LN fused into head GEMM
    rowstat<<<ROWS / 4, 256, 0, stream>>>(x, stats);
    gemm_rs<32, true, false, false, true><<<dim3(1, 256), 256, 0, stream>>>(
        x, D_, wh, whb, stats, lnf_s, lnf_b, htmp, nullptr, 32, D_);
    headsplit<<<ROWS * 16 / 256, 256, 0, stream>>>(htmp, out_logits, out_val);
    sobs_kernel<<<1, 64, 0, stream>>>(sobs, out_sobs);
}

// Round 12
// 1878.641 us; speedup vs baseline: 1.7930x; 1.1662x over previous
//
#include <hip/hip_runtime.h>
#include <hip/hip_bf16.h>
#include <math.h>

// LinearTransformerAgent R12: un-fuse LN for qkv/W1 (R11's fused-LN staging
// made GEMMs VALU-bound: MfmaUtil 17%, VALUBusy 56%, LN redundant per
// col-block). Dedicated ln_bf16 pass -> bf16 h; LNA fusion kept only in the
// head GEMM (single col-block, no redundancy). Unchunked when ws permits.

#define B_    64
#define T_    512
#define D_    512
#define H_    8
#define L_    4
#define NACT  16
#define DFF   2048
#define ROWS  (B_ * T_)
#define RC_   4

typedef __attribute__((ext_vector_type(8))) short short8;
typedef __attribute__((ext_vector_type(4))) float f32x4;
#define MFMA16(a, b, c) __builtin_amdgcn_mfma_f32_16x16x32_bf16(a, b, c, 0, 0, 0)

__device__ __forceinline__ ushort f2bf(float f) {
    union { float f; unsigned u; } c; c.f = f;
    unsigned r = c.u + 0x7FFF + ((c.u >> 16) & 1);
    return (ushort)(r >> 16);
}
__device__ __forceinline__ float gelu_tanh(float v) {
    float u = 0.7978845608028654f * (v + 0.044715f * v * v * v);
    return v - v / (1.0f + __expf(2.0f * u));
}
__device__ __forceinline__ float wave_sum(float v) {
#pragma unroll
    for (int o = 32; o > 0; o >>= 1) v += __shfl_xor(v, o);
    return v;
}
// XOR-swizzled byte offset into a [rows][128B] LDS tile
__device__ __forceinline__ int sw(int row, int kb) {
    return row * 128 + (kb ^ ((row & 7) << 4));
}
// LN 8 f32 -> 8 bf16 (packed short8) — head GEMM only
__device__ __forceinline__ short8 ln8(const float* xr, float mean, float rstd,
                                      float4 s0, float4 s1, float4 b0, float4 b1) {
    float4 a0 = *(const float4*)xr, a1 = *(const float4*)(xr + 4);
    short8 o;
    o[0] = (short)f2bf((a0.x - mean) * rstd * s0.x + b0.x);
    o[1] = (short)f2bf((a0.y - mean) * rstd * s0.y + b0.y);
    o[2] = (short)f2bf((a0.z - mean) * rstd * s0.z + b0.z);
    o[3] = (short)f2bf((a0.w - mean) * rstd * s0.w + b0.w);
    o[4] = (short)f2bf((a1.x - mean) * rstd * s1.x + b1.x);
    o[5] = (short)f2bf((a1.y - mean) * rstd * s1.y + b1.y);
    o[6] = (short)f2bf((a1.z - mean) * rstd * s1.z + b1.z);
    o[7] = (short)f2bf((a1.w - mean) * rstd * s1.w + b1.w);
    return o;
}

// ---------------------------------------------------------------- weight transpose f32 -> bf16T
__global__ __launch_bounds__(256) void wtrans(
    const float* __restrict__ W, ushort* __restrict__ Wt, int K, int N) {
    __shared__ float tb[32][33];
    const int tid = threadIdx.x, tx = tid & 31, ty = tid >> 5;
    const size_t zo = (size_t)blockIdx.z * K * N;
    const int k0 = blockIdx.x * 32, n0 = blockIdx.y * 32;
#pragma unroll
    for (int p = 0; p < 4; ++p)
        tb[ty + 8 * p][tx] = W[zo + (size_t)(k0 + ty + 8 * p) * N + n0 + tx];
    __syncthreads();
#pragma unroll
    for (int p = 0; p < 4; ++p)
        Wt[zo + (size_t)(n0 + ty + 8 * p) * K + k0 + tx] = f2bf(tb[tx][ty + 8 * p]);
}

// ---------------------------------------------------------------- f32 -> bf16 cast
__global__ __launch_bounds__(256) void castbf(
    const float* __restrict__ in, ushort* __restrict__ out) {
    const size_t i = ((size_t)blockIdx.x * 256 + threadIdx.x) * 4;
    float4 v = *(const float4*)(in + i);
    ushort4 o = { f2bf(v.x), f2bf(v.y), f2bf(v.z), f2bf(v.w) };
    *(ushort4*)(out + i) = o;
}

// ---------------------------------------------------------------- LN -> bf16 (4 rows/block)
__global__ __launch_bounds__(256) void ln_bf16_kernel(
    const float* __restrict__ x, const float* __restrict__ s,
    const float* __restrict__ b, ushort* __restrict__ o) {
    const int tid = threadIdx.x, lane = tid & 63, w = tid >> 6;
    const int row = blockIdx.x * 4 + w;
    const float4* p = (const float4*)(x + (size_t)row * D_);
    float4 a = p[lane], c = p[lane + 64];
    float sm = a.x + a.y + a.z + a.w + c.x + c.y + c.z + c.w;
    float sq = a.x*a.x + a.y*a.y + a.z*a.z + a.w*a.w
             + c.x*c.x + c.y*c.y + c.z*c.z + c.w*c.w;
    sm = wave_sum(sm);
    sq = wave_sum(sq);
    const float mean = sm * (1.0f / 512.0f);
    const float var = sq * (1.0f / 512.0f) - mean * mean;
    const float ri = rsqrtf(var + 1e-6f);
    const float4* s4 = (const float4*)s;
    const float4* b4 = (const float4*)b;
    float4 s1 = s4[lane], b1 = b4[lane];
    ushort4 o1 = { f2bf((a.x - mean) * ri * s1.x + b1.x),
                   f2bf((a.y - mean) * ri * s1.y + b1.y),
                   f2bf((a.z - mean) * ri * s1.z + b1.z),
                   f2bf((a.w - mean) * ri * s1.w + b1.w) };
    *(ushort4*)(o + (size_t)row * D_ + lane * 4) = o1;
    float4 s2 = s4[lane + 64], b2 = b4[lane + 64];
    ushort4 o2 = { f2bf((c.x - mean) * ri * s2.x + b2.x),
                   f2bf((c.y - mean) * ri * s2.y + b2.y),
                   f2bf((c.z - mean) * ri * s2.z + b2.z),
                   f2bf((c.w - mean) * ri * s2.w + b2.w) };
    *(ushort4*)(o + (size_t)row * D_ + (lane + 64) * 4) = o2;
}

// ---------------------------------------------------------------- row stats (head only)
__global__ __launch_bounds__(256) void rowstat(
    const float* __restrict__ x, float* __restrict__ stats) {
    const int w = threadIdx.x >> 6, lane = threadIdx.x & 63;
    const int row = blockIdx.x * 4 + w;
    const float4* p = (const float4*)(x + (size_t)row * D_);
    float4 a = p[lane], b = p[lane + 64];
    float s = a.x + a.y + a.z + a.w + b.x + b.y + b.z + b.w;
    float q = a.x*a.x + a.y*a.y + a.z*a.z + a.w*a.w
            + b.x*b.x + b.y*b.y + b.z*b.z + b.w*b.w;
    s = wave_sum(s);
    q = wave_sum(q);
    if (lane == 0) {
        const float mean = s * (1.0f / 512.0f);
        const float var = q * (1.0f / 512.0f) - mean * mean;
        stats[(size_t)row * 2 + 0] = mean;
        stats[(size_t)row * 2 + 1] = rsqrtf(var + 1e-6f);
    }
}

// ---------------------------------------------------------------- head weight pack
__global__ void headprep(const float* __restrict__ Wa, const float* __restrict__ ba,
                         const float* __restrict__ Wc, const float* __restrict__ bc,
                         ushort* __restrict__ wh, float* __restrict__ whb) {
    const int n = blockIdx.x, k = threadIdx.x;
    float v = (n < 16) ? Wa[(size_t)k * NACT + n] : (n == 16 ? Wc[k] : 0.0f);
    wh[(size_t)n * D_ + k] = f2bf(v);
    if (k == 0) whb[n] = (n < 16) ? ba[n] : (n == 16 ? bc[0] : 0.0f);
}

// ---------------------------------------------------------------- head output split
__global__ __launch_bounds__(256) void headsplit(
    const float* __restrict__ tmp, float* __restrict__ logits, float* __restrict__ val) {
    const size_t idx = (size_t)blockIdx.x * 256 + threadIdx.x;  // ROWS*16
    const size_t row = idx >> 4;
    const int j = (int)(idx & 15);
    logits[idx] = tmp[row * 32 + j];
    if (j == 0) val[row] = tmp[row * 32 + 16];
}

// ---------------------------------------------------------------- embed additive part
__global__ __launch_bounds__(256) void embed_add(
    const int* __restrict__ act, const float* __restrict__ rew,
    const int* __restrict__ sobs, const float* __restrict__ E_act,
    const float* __restrict__ W_rew, const float* __restrict__ b_rew,
    const float* __restrict__ E_time, float* __restrict__ x) {
    const int tid = threadIdx.x, lane = tid & 63, w = tid >> 6;
    const int row = blockIdx.x * 4 + w;
    const int b = row >> 9, t = row & 511;
    const int a = act[row];
    const float r = rew[row];
    const int ti = sobs[b] + t;
    const float4* ea = (const float4*)(E_act + (size_t)a * D_);
    const float4* et = (const float4*)(E_time + (size_t)ti * D_);
    const float4* wr4 = (const float4*)W_rew;
    const float4* br4 = (const float4*)b_rew;
    float4* xp = (float4*)(x + (size_t)row * D_);
#pragma unroll
    for (int q = 0; q < 2; ++q) {
        const int i = lane + 64 * q;
        float4 va = ea[i], vt = et[i], vw = wr4[i], vb = br4[i];
        float4 o = { vb.x + va.x + r * vw.x + vt.x,
                     vb.y + va.y + r * vw.y + vt.y,
                     vb.z + va.z + r * vw.z + vt.z,
                     vb.w + va.w + r * vw.w + vt.w };
        xp[i] = o;
    }
}

// ---------------------------------------------------------------- reg-staged MFMA GEMM
// 128xBN tile, BK=64, reg prefetch -> swizzled LDS, 2-barrier loop, XCD swizzle.
// LNA: A is f32 x, LN applied at staging (head GEMM only). Else A bf16.
// C = op(A @ Wt^T + bias); RES: f32 +=; F32ST: f32 store; else bf16 store.
template <int BN, bool LNA, bool GELU, bool RES, bool F32ST>
__global__ __launch_bounds__(256) void gemm_rs(
    const void* __restrict__ Av, int lda,
    const ushort* __restrict__ Wt,
    const float* __restrict__ bias,
    const float* __restrict__ stats,
    const float* __restrict__ lns, const float* __restrict__ lnb,
    float* __restrict__ Cf, ushort* __restrict__ Cb, int ldc,
    int K) {
    constexpr int NJ = BN / 32;
    __shared__ ushort As[128 * 64];
    __shared__ ushort Bs[BN * 64];
    const int tid = threadIdx.x, lane = tid & 63, wid = tid >> 6;
    const int wr = wid >> 1, wc = wid & 1;
    const int lr = lane & 15, lg = lane >> 4;

    // XCD swizzle (all launches have nwg % 8 == 0)
    const int nx = gridDim.x;
    int lin = blockIdx.y * nx + blockIdx.x;
    const int qq = (nx * gridDim.y) >> 3;
    lin = (lin & 7) * qq + (lin >> 3);
    const int row0 = (lin / nx) * 128, col0 = (lin % nx) * BN;

    f32x4 zero = {0.f, 0.f, 0.f, 0.f};
    f32x4 acc[4][NJ];
#pragma unroll
    for (int i = 0; i < 4; ++i)
#pragma unroll
        for (int j = 0; j < NJ; ++j) acc[i][j] = zero;

    const int smb = tid >> 3, sk = (tid & 7) * 8;
    const int soff = smb * 128 + ((sk * 2) ^ ((smb & 7) << 4));
    const float*  Af = (const float*)Av;
    const ushort* Ab = (const ushort*)Av;
    const ushort* Bp = Wt + (size_t)(col0 + smb) * K + sk;

    float mean_[4], rstd_[4];
    if (LNA) {
#pragma unroll
        for (int p = 0; p < 4; ++p) {
            const int rr = row0 + smb + 32 * p;
            mean_[p] = stats[(size_t)rr * 2 + 0];
            rstd_[p] = stats[(size_t)rr * 2 + 1];
        }
    }

    short8 ra[4], rb[NJ];
    if (LNA) {
        float4 s0 = *(const float4*)(lns + sk), s1 = *(const float4*)(lns + sk + 4);
        float4 b0 = *(const float4*)(lnb + sk), b1 = *(const float4*)(lnb + sk + 4);
#pragma unroll
        for (int p = 0; p < 4; ++p)
            ra[p] = ln8(Af + (size_t)(row0 + smb + 32 * p) * lda + sk,
                        mean_[p], rstd_[p], s0, s1, b0, b1);
    } else {
#pragma unroll
        for (int p = 0; p < 4; ++p)
            ra[p] = *(const short8*)(Ab + (size_t)(row0 + smb + 32 * p) * lda + sk);
    }
#pragma unroll
    for (int p = 0; p < NJ; ++p) rb[p] = *(const short8*)(Bp + (size_t)(32 * p) * K);

    for (int k0 = 0;;) {
        __syncthreads();
#pragma unroll
        for (int p = 0; p < 4; ++p) *(short8*)((char*)As + soff + p * 4096) = ra[p];
#pragma unroll
        for (int p = 0; p < NJ; ++p) *(short8*)((char*)Bs + soff + p * 4096) = rb[p];
        __syncthreads();
        k0 += 64;
        if (k0 < K) {
            if (LNA) {
                float4 s0 = *(const float4*)(lns + k0 + sk);
                float4 s1 = *(const float4*)(lns + k0 + sk + 4);
                float4 b0 = *(const float4*)(lnb + k0 + sk);
                float4 b1 = *(const float4*)(lnb + k0 + sk + 4);
#pragma unroll
                for (int p = 0; p < 4; ++p)
                    ra[p] = ln8(Af + (size_t)(row0 + smb + 32 * p) * lda + k0 + sk,
                                mean_[p], rstd_[p], s0, s1, b0, b1);
            } else {
#pragma unroll
                for (int p = 0; p < 4; ++p)
                    ra[p] = *(const short8*)(Ab + (size_t)(row0 + smb + 32 * p) * lda + k0 + sk);
            }
#pragma unroll
            for (int p = 0; p < NJ; ++p)
                rb[p] = *(const short8*)(Bp + (size_t)(32 * p) * K + k0);
        }
#pragma unroll
        for (int k2 = 0; k2 < 2; ++k2) {
            short8 af[4], bf[NJ];
#pragma unroll
            for (int i = 0; i < 4; ++i)
                af[i] = *(const short8*)((char*)As + sw(64 * wr + 16 * i + lr, k2 * 64 + lg * 16));
#pragma unroll
            for (int j = 0; j < NJ; ++j)
                bf[j] = *(const short8*)((char*)Bs + sw((BN / 2) * wc + 16 * j + lr, k2 * 64 + lg * 16));
#pragma unroll
            for (int i = 0; i < 4; ++i)
#pragma unroll
                for (int j = 0; j < NJ; ++j) acc[i][j] = MFMA16(af[i], bf[j], acc[i][j]);
        }
        if (k0 >= K) break;
    }

#pragma unroll
    for (int j = 0; j < NJ; ++j) {
        const int col = col0 + (BN / 2) * wc + 16 * j + lr;
        const float bj = bias[col];
#pragma unroll
        for (int i = 0; i < 4; ++i) {
            const int rbase = row0 + 64 * wr + 16 * i + lg * 4;
#pragma unroll
            for (int r = 0; r < 4; ++r) {
                float v = acc[i][j][r] + bj;
                if (GELU) v = gelu_tanh(v);
                if (RES) {
                    float* p = Cf + (size_t)(rbase + r) * ldc + col;
                    *p = *p + v;
                } else if (F32ST) {
                    Cf[(size_t)(rbase + r) * ldc + col] = v;
                } else {
                    Cb[(size_t)(rbase + r) * ldc + col] = f2bf(v);
                }
            }
        }
    }
}

// ---------------------------------------------------------------- MFMA linear attention
__global__ __launch_bounds__(256) void attn_bf16(
    ushort* __restrict__ qkv, const float* __restrict__ sin_,
    float* __restrict__ sout, int layer, int b0) {
    __shared__ ushort Qs[4096], Ks[4096], Kt[4096], Vt[4096], Ps[4096], Stb[4096];
    const int tid = threadIdx.x, lane = tid & 63, w = tid >> 6;
    const int lr = lane & 15, lg = lane >> 4;
    const int bh = blockIdx.x, bl = bh >> 3, h = bh & 7;
    const size_t soff = (((size_t)(b0 + bl) * L_ + layer) * H_ + h) * 4096;

    f32x4 zero = {0.f, 0.f, 0.f, 0.f};
    f32x4 stacc[4];
#pragma unroll
    for (int n = 0; n < 4; ++n)
#pragma unroll
        for (int r = 0; r < 4; ++r)
            stacc[n][r] = sin_[soff + (size_t)(16 * n + lr) * 64 + 16 * w + lg * 4 + r];

    const int st = tid >> 3, sd8 = (tid & 7) * 8;

    short8 rq[2], rk[2], rv[2];
#pragma unroll
    for (int p = 0; p < 2; ++p) {
        const ushort* g = qkv + (size_t)(bl * T_ + st + 32 * p) * 1536 + h * 64;
        rq[p] = *(const short8*)(g + sd8);
        rk[p] = *(const short8*)(g + 512 + sd8);
        rv[p] = *(const short8*)(g + 1024 + sd8);
    }

    for (int tile = 0; tile < 8; ++tile) {
#pragma unroll
        for (int p = 0; p < 2; ++p) {
            const int t = st + 32 * p;
            *(short8*)((char*)Qs + sw(t, sd8 * 2)) = rq[p];
            *(short8*)((char*)Ks + sw(t, sd8 * 2)) = rk[p];
#pragma unroll
            for (int j = 0; j < 8; ++j) {
                *(ushort*)((char*)Kt + sw(sd8 + j, t * 2)) = (ushort)rk[p][j];
                *(ushort*)((char*)Vt + sw(sd8 + j, t * 2)) = (ushort)rv[p][j];
            }
        }
#pragma unroll
        for (int n = 0; n < 4; ++n)
#pragma unroll
            for (int r = 0; r < 4; ++r)
                *(ushort*)((char*)Stb + sw(16 * w + lg * 4 + r, (16 * n + lr) * 2)) =
                    f2bf(stacc[n][r]);
        __syncthreads();

        if (tile < 7) {
            const int t1 = (tile + 1) * 64;
#pragma unroll
            for (int p = 0; p < 2; ++p) {
                const ushort* g = qkv + (size_t)(bl * T_ + t1 + st + 32 * p) * 1536 + h * 64;
                rq[p] = *(const short8*)(g + sd8);
                rk[p] = *(const short8*)(g + 512 + sd8);
                rv[p] = *(const short8*)(g + 1024 + sd8);
            }
        }

        short8 aq[2];
#pragma unroll
        for (int k2 = 0; k2 < 2; ++k2)
            aq[k2] = *(const short8*)((char*)Qs + sw(16 * w + lr, k2 * 64 + lg * 16));

        f32x4 pacc[4], oacc[4];
#pragma unroll
        for (int n = 0; n < 4; ++n) { pacc[n] = zero; oacc[n] = zero; }
#pragma unroll
        for (int k2 = 0; k2 < 2; ++k2)
#pragma unroll
            for (int n = 0; n < 4; ++n) {
                short8 bk = *(const short8*)((char*)Ks + sw(16 * n + lr, k2 * 64 + lg * 16));
                pacc[n] = MFMA16(aq[k2], bk, pacc[n]);
            }
#pragma unroll
        for (int k2 = 0; k2 < 2; ++k2)
#pragma unroll
            for (int n = 0; n < 4; ++n) {
                short8 bs = *(const short8*)((char*)Stb + sw(16 * n + lr, k2 * 64 + lg * 16));
                oacc[n] = MFMA16(aq[k2], bs, oacc[n]);
            }
#pragma unroll
        for (int n = 0; n < 4; ++n)
#pragma unroll
            for (int r = 0; r < 4; ++r) {
                const int t = 16 * w + lg * 4 + r, s = 16 * n + lr;
                *(ushort*)((char*)Ps + sw(t, s * 2)) =
                    (s <= t) ? f2bf(pacc[n][r]) : (ushort)0;
            }
        short8 ap[2], av[2];
#pragma unroll
        for (int k2 = 0; k2 < 2; ++k2) {
            ap[k2] = *(const short8*)((char*)Ps + sw(16 * w + lr, k2 * 64 + lg * 16));
            av[k2] = *(const short8*)((char*)Vt + sw(16 * w + lr, k2 * 64 + lg * 16));
        }
#pragma unroll
        for (int k2 = 0; k2 < 2; ++k2)
#pragma unroll
            for (int n = 0; n < 4; ++n) {
                short8 bv = *(const short8*)((char*)Vt + sw(16 * n + lr, k2 * 64 + lg * 16));
                oacc[n] = MFMA16(ap[k2], bv, oacc[n]);
            }
#pragma unroll
        for (int k2 = 0; k2 < 2; ++k2)
#pragma unroll
            for (int n = 0; n < 4; ++n) {
                short8 bkt = *(const short8*)((char*)Kt + sw(16 * n + lr, k2 * 64 + lg * 16));
                stacc[n] = MFMA16(av[k2], bkt, stacc[n]);
            }
#pragma unroll
        for (int n = 0; n < 4; ++n)
#pragma unroll
            for (int r = 0; r < 4; ++r) {
                const int t = 16 * w + lg * 4 + r, e = 16 * n + lr;
                qkv[(size_t)(bl * T_ + tile * 64 + t) * 1536 + h * 64 + e] = f2bf(oacc[n][r]);
            }
        __syncthreads();
    }
#pragma unroll
    for (int n = 0; n < 4; ++n)
#pragma unroll
        for (int r = 0; r < 4; ++r)
            sout[soff + (size_t)(16 * n + lr) * 64 + 16 * w + lg * 4 + r] = stacc[n][r];
}

__global__ void sobs_kernel(const int* __restrict__ sobs, float* __restrict__ out) {
    const int i = threadIdx.x;
    if (i < B_) out[i] = (float)(sobs[i] + T_);
}

// ---------------------------------------------------------------- launch
extern "C" void kernel_launch(void* const* d_in, const int* in_sizes, int n_in,
                              void* d_out, int out_size, void* d_ws, size_t ws_size,
                              hipStream_t stream) {
    const float* obs     = (const float*)d_in[0];
    const int*   act_p   = (const int*)d_in[1];
    const float* rew_p   = (const float*)d_in[2];
    const int*   sobs    = (const int*)d_in[3];
    const float* sblk    = (const float*)d_in[4];
    const float* W_obs   = (const float*)d_in[5];
    const float* b_obs   = (const float*)d_in[6];
    const float* E_act   = (const float*)d_in[7];
    const float* W_rew   = (const float*)d_in[8];
    const float* b_rew   = (const float*)d_in[9];
    const float* E_time  = (const float*)d_in[10];
    const float* ln1_s   = (const float*)d_in[11];
    const float* ln1_b   = (const float*)d_in[12];
    const float* Wqkv    = (const float*)d_in[13];
    const float* bqkv    = (const float*)d_in[14];
    const float* Wout    = (const float*)d_in[15];
    const float* bout    = (const float*)d_in[16];
    const float* ln2_s   = (const float*)d_in[17];
    const float* ln2_b   = (const float*)d_in[18];
    const float* W1      = (const float*)d_in[19];
    const float* b1      = (const float*)d_in[20];
    const float* W2      = (const float*)d_in[21];
    const float* b2      = (const float*)d_in[22];
    const float* lnf_s   = (const float*)d_in[23];
    const float* lnf_b   = (const float*)d_in[24];
    const float* W_actor = (const float*)d_in[25];
    const float* b_actor = (const float*)d_in[26];
    const float* W_crit  = (const float*)d_in[27];
    const float* b_crit  = (const float*)d_in[28];

    float* out        = (float*)d_out;
    float* out_blocks = out;
    float* out_sobs   = out + (size_t)B_ * L_ * H_ * 64 * 64;
    float* out_logits = out_sobs + B_;
    float* out_val    = out_logits + (size_t)ROWS * NACT;

    const size_t wbytes = ((size_t)L_ * (D_ * 3 * D_ + D_ * D_ + 2 * D_ * DFF)) * 2;
    auto need_for = [&](int chrows) {
        return (size_t)ROWS * D_ * 4 + (size_t)chrows * DFF * 2
             + (size_t)chrows * D_ * 2 + wbytes
             + (size_t)ROWS * 64 * 2 + (size_t)D_ * 64 * 2
             + (size_t)32 * D_ * 2 + 32 * 4 + (size_t)ROWS * 2 * 4;
    };
    const int rcn = (ws_size >= need_for(ROWS)) ? 1 : RC_;
    const int chrows = ROWS / rcn, chb = B_ / rcn;
    if (ws_size < need_for(chrows)) return;  // fail soft

    float*  x    = (float*)d_ws;                        // ROWS*512 f32
    ushort* big  = (ushort*)(x + (size_t)ROWS * D_);    // chrows*2048 bf16
    ushort* h    = big + (size_t)chrows * DFF;          // chrows*512 bf16
    ushort* wq   = h + (size_t)chrows * D_;
    ushort* wo   = wq + (size_t)L_ * D_ * 3 * D_;
    ushort* w1t  = wo + (size_t)L_ * D_ * D_;
    ushort* w2t  = w1t + (size_t)L_ * D_ * DFF;
    ushort* obsb = w2t + (size_t)L_ * DFF * D_;         // ROWS*64 bf16
    ushort* wob  = obsb + (size_t)ROWS * 64;            // 512*64
    ushort* wh   = wob + (size_t)D_ * 64;               // 32*512
    float*  whb  = (float*)(wh + 32 * D_);              // 32
    float*  stats = whb + 32;                           // ROWS*2 f32
    float*  htmp = (float*)obsb;                        // ROWS*32 f32 (reuse)

    wtrans<<<dim3(16, 48, L_), 256, 0, stream>>>(Wqkv, wq, D_, 3 * D_);
    wtrans<<<dim3(16, 16, L_), 256, 0, stream>>>(Wout, wo, D_, D_);
    wtrans<<<dim3(16, 64, L_), 256, 0, stream>>>(W1, w1t, D_, DFF);
    wtrans<<<dim3(64, 16, L_), 256, 0, stream>>>(W2, w2t, DFF, D_);
    wtrans<<<dim3(2, 16, 1), 256, 0, stream>>>(W_obs, wob, 64, D_);
    castbf<<<ROWS * 64 / 1024, 256, 0, stream>>>(obs, obsb);
    headprep<<<32, 512, 0, stream>>>(W_actor, b_actor, W_crit, b_crit, wh, whb);

    embed_add<<<ROWS / 4, 256, 0, stream>>>(act_p, rew_p, sobs, E_act, W_rew,
                                            b_rew, E_time, x);
    gemm_rs<128, false, false, true, false><<<dim3(4, 256), 256, 0, stream>>>(
        obsb, 64, wob, b_obs, nullptr, nullptr, nullptr, x, nullptr, D_, 64);

    for (int l = 0; l < L_; ++l) {
        for (int rc = 0; rc < rcn; ++rc) {
            const size_t ro = (size_t)rc * chrows;
            ln_bf16_kernel<<<chrows / 4, 256, 0, stream>>>(
                x + ro * D_, ln1_s + l * D_, ln1_b + l * D_, h);
            gemm_rs<128, false, false, false, false><<<dim3(12, chrows / 128), 256, 0, stream>>>(
                h, D_, wq + (size_t)l * D_ * 3 * D_, bqkv + l * 3 * D_,
                nullptr, nullptr, nullptr, nullptr, big, 3 * D_, D_);
            attn_bf16<<<chb * H_, 256, 0, stream>>>(big, sblk, out_blocks, l, rc * chb);
            gemm_rs<64, false, false, true, false><<<dim3(8, chrows / 128), 256, 0, stream>>>(
                big, 3 * D_, wo + (size_t)l * D_ * D_, bout + l * D_,
                nullptr, nullptr, nullptr, x + ro * D_, nullptr, D_, D_);
            ln_bf16_kernel<<<chrows / 4, 256, 0, stream>>>(
                x + ro * D_, ln2_s + l * D_, ln2_b + l * D_, h);
            gemm_rs<128, false, true, false, false><<<dim3(16, chrows / 128), 256, 0, stream>>>(
                h, D_, w1t + (size_t)l * D_ * DFF, b1 + l * DFF,
                nullptr, nullptr, nullptr, nullptr, big, DFF, D_);
            gemm_rs<64, false, false, true, false><<<dim3(8, chrows / 128), 256, 0, stream>>>(
                big, DFF, w2t + (size_t)l * DFF * D_, b2 + l * D_,
                nullptr, nullptr, nullptr, x + ro * D_, nullptr, D_, DFF);
        }
    }
    // final LN fused into head GEMM (single col-block: no redundancy)
    rowstat<<<ROWS / 4, 256, 0, stream>>>(x, stats);
    gemm_rs<32, true, false, false, true><<<dim3(1, 256), 256, 0, stream>>>(
        x, D_, wh, whb, stats, lnf_s, lnf_b, htmp, nullptr, 32, D_);
    headsplit<<<ROWS * 16 / 256, 256, 0, stream>>>(htmp, out_logits, out_val);
    sobs_kernel<<<1, 64, 0, stream>>>(sobs, out_sobs);
}